// Round 1
// 361.355 us; speedup vs baseline: 1.3084x; 1.3084x over previous
//
#include <hip/hip_runtime.h>
#include <hip/hip_bf16.h>

// B=2, S=2048, D=1024, H=16, HD=64, RANK=8, ALPHA=8. ALL I/O FP32.
// R13 = R12 with attn_mfma restructured:
//  - double-buffered K/V LDS, ONE barrier per 64-key chunk (was 3)
//  - chunk c+1 global loads issued before chunk c compute (latency hidden)
//  - V staged via key-axis coalesced loads -> dense vector LDS writes
//    (kills the 16-way scatter-transpose bank conflicts)
//  - Pt padded [16]->[17] rows (8-way -> 4-way write conflicts)
//  - q-tile pairing (x with 31-x): every block = exactly 33 chunks,
//    grid 512 = 2 blocks/CU resident, no imbalance tail
// prep/gemm3 byte-identical to R12 (hardware-validated).
// ws (60 MB): qkf 0-32 | vbb 32-40 | wpt hi 40-42 lo 42-44 |
//             wqt hi 44-50 lo 50-56 | ctxf 44-60 (overlays dead wqt).

#define BB    2
#define SS    2048
#define DD    1024
#define HH    16
#define HDIM  64
#define N3    3072
#define MR    4096

typedef short short8 __attribute__((ext_vector_type(8)));
typedef float f32x4 __attribute__((ext_vector_type(4)));

#define MFMA16(a, b, c) __builtin_amdgcn_mfma_f32_16x16x32_bf16((a), (b), (c), 0, 0, 0)

__device__ __forceinline__ float b2f(short s) {
    union { unsigned int u; float f; } c;
    c.u = ((unsigned int)(unsigned short)s) << 16;
    return c.f;
}
__device__ __forceinline__ short f2b(float f) {
    union { __hip_bfloat16 h; short s; } c;
    c.h = __float2bfloat16(f);
    return c.s;
}
struct HiLo { short hi, lo; };
__device__ __forceinline__ HiLo split2(float v) {
    HiLo r;
    r.hi = f2b(v);
    r.lo = f2b(v - b2f(r.hi));   // exact residual; next 8 mantissa bits
    return r;
}

// ---------------------------------------------------------------- prep
// Whi/Wlo[n][k] = bf16split( W[k][n] + lora*8*sum_r A[k][r]*B[r][n] ), fp32 in.
__global__ __launch_bounds__(256) void prep_kernel(
    const float* __restrict__ W, const float* __restrict__ Al,
    const float* __restrict__ Bl, short* __restrict__ Whi,
    short* __restrict__ Wlo, int N, int lora)
{
    __shared__ float sw[64][68];
    __shared__ float sa[64][8];
    __shared__ float sb[8][64];
    int tid = threadIdx.x;
    int n0 = blockIdx.x * 64, k0 = blockIdx.y * 64;
#pragma unroll
    for (int p = 0; p < 4; p++) {
        int idx = p * 256 + tid;
        int kr = idx >> 4, ch = idx & 15;
        *(f32x4*)&sw[kr][ch * 4] = *(const f32x4*)&W[(size_t)(k0 + kr) * N + n0 + ch * 4];
    }
    if (lora) {
        if (tid < 64) {
#pragma unroll
            for (int r = 0; r < 8; r++) sa[tid][r] = Al[(k0 + tid) * 8 + r];
        } else if (tid < 128) {
            int c = tid - 64;
#pragma unroll
            for (int r = 0; r < 8; r++) sb[r][c] = Bl[(size_t)r * N + n0 + c];
        }
    }
    __syncthreads();
#pragma unroll
    for (int p = 0; p < 2; p++) {
        int idx = p * 256 + tid;
        int nr = idx >> 3, ch = idx & 7;
        short8 h8, l8;
#pragma unroll
        for (int j = 0; j < 8; j++) {
            int k = ch * 8 + j;
            float v = sw[k][nr];
            if (lora) {
                float a2 = 0.f;
#pragma unroll
                for (int r = 0; r < 8; r++) a2 += sa[k][r] * sb[r][nr];
                v += 8.0f * a2;
            }
            HiLo hl = split2(v);
            h8[j] = hl.hi;
            l8[j] = hl.lo;
        }
        size_t off = (size_t)(n0 + nr) * 1024 + k0 + ch * 8;
        *(short8*)&Whi[off] = h8;
        *(short8*)&Wlo[off] = l8;
    }
}

// ---------------------------------------------------------------- gemm3
// C[m][n] = sum_k Af[m][k]*(Bhi+Blo)[n][k] + bias[n]; A fp32 split on the fly.
__global__ __launch_bounds__(256) void gemm3(
    const float* __restrict__ Af, const short* __restrict__ Bhi,
    const short* __restrict__ Blo, const float* __restrict__ bias,
    float* __restrict__ outqk, short* __restrict__ outv,
    float* __restrict__ outf32, int N, int mode)
{
    __shared__ short Ah[4][128][8];
    __shared__ short Alo[4][128][8];
    __shared__ short Bh[4][128][8];
    __shared__ short Blo_s[4][128][8];
    int tid = threadIdx.x;
    int wav = tid >> 6, lane = tid & 63;
    int l15 = lane & 15, q4 = lane >> 4;
    int wm = wav & 1, wn = wav >> 1;
    int n0 = blockIdx.x * 128, m0 = blockIdx.y * 128;

    f32x4 acc[4][4] = {};
    int srow = tid >> 2, skq = tid & 3;

    for (int kk = 0; kk < 1024; kk += 32) {
        __syncthreads();
#pragma unroll
        for (int half = 0; half < 2; half++) {
            int row = srow + half * 64;
            const float* src = &Af[(size_t)(m0 + row) * 1024 + kk + skq * 8];
            f32x4 v0 = *(const f32x4*)src;
            f32x4 v1 = *(const f32x4*)(src + 4);
            short8 h8, l8;
#pragma unroll
            for (int j = 0; j < 4; j++) {
                HiLo hl = split2(v0[j]);
                h8[j] = hl.hi; l8[j] = hl.lo;
            }
#pragma unroll
            for (int j = 0; j < 4; j++) {
                HiLo hl = split2(v1[j]);
                h8[4 + j] = hl.hi; l8[4 + j] = hl.lo;
            }
            *(short8*)&Ah[skq][row][0]  = h8;
            *(short8*)&Alo[skq][row][0] = l8;
            size_t boff = (size_t)(n0 + row) * 1024 + kk + skq * 8;
            *(short8*)&Bh[skq][row][0]    = *(const short8*)&Bhi[boff];
            *(short8*)&Blo_s[skq][row][0] = *(const short8*)&Blo[boff];
        }
        __syncthreads();
        short8 ah[4], al_[4], bh[4], bl[4];
#pragma unroll
        for (int i = 0; i < 4; i++) {
            ah[i]  = *(short8*)&Ah[q4][wm * 64 + i * 16 + l15][0];
            al_[i] = *(short8*)&Alo[q4][wm * 64 + i * 16 + l15][0];
            bh[i]  = *(short8*)&Bh[q4][wn * 64 + i * 16 + l15][0];
            bl[i]  = *(short8*)&Blo_s[q4][wn * 64 + i * 16 + l15][0];
        }
#pragma unroll
        for (int mi = 0; mi < 4; mi++)
#pragma unroll
            for (int ni = 0; ni < 4; ni++) {
                acc[mi][ni] = MFMA16(ah[mi], bh[ni], acc[mi][ni]);
                acc[mi][ni] = MFMA16(ah[mi], bl[ni], acc[mi][ni]);
                acc[mi][ni] = MFMA16(al_[mi], bh[ni], acc[mi][ni]);
            }
    }
#pragma unroll
    for (int ni = 0; ni < 4; ni++) {
        int n = n0 + wn * 64 + ni * 16 + l15;
        float bv = bias[n];
#pragma unroll
        for (int mi = 0; mi < 4; mi++) {
            int mbase = m0 + wm * 64 + mi * 16 + q4 * 4;
#pragma unroll
            for (int r = 0; r < 4; r++) {
                int m = mbase + r;
                float v = acc[mi][ni][r] + bv;
                if (mode == 0) {
                    if (n < 2048) outqk[(size_t)m * 2048 + n] = v;
                    else          outv[(size_t)m * 1024 + (n - 2048)] = f2b(v);
                } else {
                    outf32[(size_t)m * 1024 + n] = v;
                }
            }
        }
    }
}

// ---------------------------------------------------------------- attn_mfma
// grid (S/128, H, B) = 512 blocks; block x processes q-tiles {31-x, x}
// (33 chunks each -> perfect balance, 2 blocks/CU resident).
// Per 64-key chunk: double-buffered K(hi/lo) + V^T in LDS, prefetch c+1
// into regs before computing c, stage to LDS[cur^1] after PV, ONE barrier.
__global__ __launch_bounds__(256) void attn_mfma(const float* __restrict__ qk,
                                                 const short* __restrict__ vb,
                                                 float* __restrict__ ctxf) {
    __shared__ short Kh[2][8][64][8];      // [buf][hd-octet][key][j]  hi
    __shared__ short Kl[2][8][64][8];      //                          lo
    __shared__ short Vt[2][8][64][8];      // [buf][key-octet][hd][key&7]
    __shared__ short Pt[4][8][17][8];      // [wave][key-octet][qrow(+pad)][j]

    int h = blockIdx.y, b = blockIdx.z;
    int tid = threadIdx.x, wav = tid >> 6, lane = tid & 63;
    int l15 = lane & 15, q4 = lane >> 4;
    int skey = tid >> 3, sch = tid & 7;          // K staging coords
    const float* bqk = qk + (size_t)b * SS * 2048;
    const short* bv  = vb + (size_t)b * SS * 1024;

    // prefetch registers (chunk c+1 lives here during chunk c's compute)
    f32x4 ka[2][2];
    short vr[16];

#define LOADKV(c)                                                               \
    {                                                                           \
        int kk_ = (c) * 64;                                                     \
        const float* ks_ = &bqk[(size_t)(kk_ + skey) * 2048 + 1024 + h * 64 + sch * 8]; \
        ka[0][0] = *(const f32x4*)ks_;                                          \
        ka[0][1] = *(const f32x4*)(ks_ + 4);                                    \
        ka[1][0] = *(const f32x4*)(ks_ + 32 * 2048);                            \
        ka[1][1] = *(const f32x4*)(ks_ + 32 * 2048 + 4);                        \
        const short* vs_ = &bv[(size_t)(kk_ + wav * 16) * 1024 + h * 64 + lane]; \
        _Pragma("unroll") for (int j_ = 0; j_ < 16; ++j_) vr[j_] = vs_[(size_t)j_ * 1024]; \
    }

#define STAGEKV(buf)                                                            \
    {                                                                           \
        _Pragma("unroll") for (int p_ = 0; p_ < 2; ++p_) {                      \
            short8 h8_, l8_;                                                    \
            _Pragma("unroll") for (int j_ = 0; j_ < 4; ++j_) {                  \
                HiLo u_ = split2(ka[p_][0][j_]); h8_[j_] = u_.hi; l8_[j_] = u_.lo; \
                HiLo w_ = split2(ka[p_][1][j_]); h8_[4 + j_] = w_.hi; l8_[4 + j_] = w_.lo; \
            }                                                                   \
            int key_ = p_ * 32 + skey;                                          \
            *(short8*)&Kh[buf][sch][key_][0] = h8_;                             \
            *(short8*)&Kl[buf][sch][key_][0] = l8_;                             \
        }                                                                       \
        short8 v0_, v1_;                                                        \
        _Pragma("unroll") for (int j_ = 0; j_ < 8; ++j_) { v0_[j_] = vr[j_]; v1_[j_] = vr[8 + j_]; } \
        *(short8*)&Vt[buf][wav * 2][lane][0] = v0_;                             \
        *(short8*)&Vt[buf][wav * 2 + 1][lane][0] = v1_;                         \
    }

    for (int t = 0; t < 2; ++t) {
        int qt = t ? (int)blockIdx.x : 31 - (int)blockIdx.x;
        int qb = qt * 64;

        // Q fragments: rows qb+wav*16+l15, hd = q4*8+j (+32 for second k-step)
        size_t qoff = (size_t)(qb + wav * 16 + l15) * 2048 + h * 64;
        short8 q0h, q0l, q1h, q1l;
        {
            f32x4 a0 = *(const f32x4*)&bqk[qoff + q4 * 8];
            f32x4 a1 = *(const f32x4*)&bqk[qoff + q4 * 8 + 4];
            f32x4 c0 = *(const f32x4*)&bqk[qoff + 32 + q4 * 8];
            f32x4 c1 = *(const f32x4*)&bqk[qoff + 32 + q4 * 8 + 4];
#pragma unroll
            for (int j = 0; j < 4; j++) {
                HiLo u = split2(a0[j]); q0h[j] = u.hi; q0l[j] = u.lo;
                HiLo v = split2(a1[j]); q0h[4 + j] = v.hi; q0l[4 + j] = v.lo;
                HiLo w = split2(c0[j]); q1h[j] = w.hi; q1l[j] = w.lo;
                HiLo z = split2(c1[j]); q1h[4 + j] = z.hi; q1l[4 + j] = z.lo;
            }
        }

        f32x4 o[4] = {};
        float m[4]  = {-1e30f, -1e30f, -1e30f, -1e30f};
        float lsum[4] = {0.f, 0.f, 0.f, 0.f};
        int nch = qt + 1;

        // prologue: stage chunk 0
        LOADKV(0);
        STAGEKV(0);
        __syncthreads();

        for (int c = 0; c < nch; ++c) {
            int cur = c & 1;
            int k0 = c * 64;

            // issue next chunk's global loads early (latency hidden by compute)
            if (c + 1 < nch) LOADKV(c + 1);

            // ---- scores: 4 groups of 16 keys, 6 MFMAs each (hi/lo)
            f32x4 s[4];
#pragma unroll
            for (int g = 0; g < 4; g++) {
                short8 k0h_ = *(short8*)&Kh[cur][q4][g * 16 + l15][0];
                short8 k0l_ = *(short8*)&Kl[cur][q4][g * 16 + l15][0];
                short8 k1h_ = *(short8*)&Kh[cur][4 + q4][g * 16 + l15][0];
                short8 k1l_ = *(short8*)&Kl[cur][4 + q4][g * 16 + l15][0];
                f32x4 acc = {};
                acc = MFMA16(q0h, k0h_, acc);
                acc = MFMA16(q0h, k0l_, acc);
                acc = MFMA16(q0l, k0h_, acc);
                acc = MFMA16(q1h, k1h_, acc);
                acc = MFMA16(q1h, k1l_, acc);
                acc = MFMA16(q1l, k1h_, acc);
                s[g] = acc;
            }

            // ---- online softmax per row r (C layout: col=l15 key, row=q4*4+r)
            float alpha[4];
#pragma unroll
            for (int r = 0; r < 4; r++) {
                int q = qb + wav * 16 + q4 * 4 + r;
                float a[4];
#pragma unroll
                for (int g = 0; g < 4; g++) {
                    int key = k0 + g * 16 + l15;
                    a[g] = (key <= q) ? s[g][r] * 0.125f : -1e30f;
                }
                float mx = fmaxf(fmaxf(a[0], a[1]), fmaxf(a[2], a[3]));
                mx = fmaxf(mx, __shfl_xor(mx, 1, 64));
                mx = fmaxf(mx, __shfl_xor(mx, 2, 64));
                mx = fmaxf(mx, __shfl_xor(mx, 4, 64));
                mx = fmaxf(mx, __shfl_xor(mx, 8, 64));
                float mn = fmaxf(m[r], mx);
                float p0 = __expf(a[0] - mn), p1 = __expf(a[1] - mn);
                float p2 = __expf(a[2] - mn), p3 = __expf(a[3] - mn);
                float sm = p0 + p1 + p2 + p3;
                sm += __shfl_xor(sm, 1, 64);
                sm += __shfl_xor(sm, 2, 64);
                sm += __shfl_xor(sm, 4, 64);
                sm += __shfl_xor(sm, 8, 64);
                alpha[r] = __expf(m[r] - mn);
                m[r] = mn;
                lsum[r] = lsum[r] * alpha[r] + sm;
                int kq = (l15 >> 3), j = l15 & 7, row = q4 * 4 + r;
                Pt[wav][0 + kq][row][j] = f2b(p0);
                Pt[wav][2 + kq][row][j] = f2b(p1);
                Pt[wav][4 + kq][row][j] = f2b(p2);
                Pt[wav][6 + kq][row][j] = f2b(p3);
            }
            // Pt is per-wave (written+read by the same wave): no barrier needed.
            // Vt[cur] was published by last iteration's barrier.

            // ---- PV: A = P (keys 0..31 / 32..63), B = V^T
            short8 pf0 = *(short8*)&Pt[wav][q4][l15][0];
            short8 pf1 = *(short8*)&Pt[wav][4 + q4][l15][0];
#pragma unroll
            for (int gg = 0; gg < 4; gg++) {
                short8 vf0 = *(short8*)&Vt[cur][q4][gg * 16 + l15][0];
                short8 vf1 = *(short8*)&Vt[cur][4 + q4][gg * 16 + l15][0];
                f32x4 tt = o[gg];
                tt[0] *= alpha[0]; tt[1] *= alpha[1]; tt[2] *= alpha[2]; tt[3] *= alpha[3];
                tt = MFMA16(pf0, vf0, tt);
                tt = MFMA16(pf1, vf1, tt);
                o[gg] = tt;
            }

            // stage chunk c+1 into the other buffer; single barrier per chunk
            if (c + 1 < nch) STAGEKV(cur ^ 1);
            __syncthreads();
        }

#pragma unroll
        for (int gg = 0; gg < 4; gg++)
#pragma unroll
            for (int r = 0; r < 4; r++) {
                int q = qb + wav * 16 + q4 * 4 + r;
                ctxf[((size_t)b * SS + q) * 1024 + h * 64 + gg * 16 + l15] =
                    o[gg][r] / lsum[r];
            }
    }
#undef LOADKV
#undef STAGEKV
}

extern "C" void kernel_launch(void* const* d_in, const int* in_sizes, int n_in,
                              void* d_out, int out_size, void* d_ws, size_t ws_size,
                              hipStream_t stream) {
    const float* x  = (const float*)d_in[0];
    const float* Wq = (const float*)d_in[1];
    const float* bq = (const float*)d_in[2];
    const float* Al = (const float*)d_in[3];
    const float* Bl = (const float*)d_in[4];
    const float* Wp = (const float*)d_in[5];
    const float* bp = (const float*)d_in[6];

    char* ws = (char*)d_ws;
    float* qkf    = (float*)(ws);                             // 0-32 MB
    short* vbb    = (short*)(ws + (size_t)32 * 1024 * 1024);  // 32-40
    short* wpt_hi = (short*)(ws + (size_t)40 * 1024 * 1024);  // 40-42
    short* wpt_lo = (short*)(ws + (size_t)42 * 1024 * 1024);  // 42-44
    short* wqt_hi = (short*)(ws + (size_t)44 * 1024 * 1024);  // 44-50
    short* wqt_lo = (short*)(ws + (size_t)50 * 1024 * 1024);  // 50-56
    float* ctxf   = (float*)(ws + (size_t)44 * 1024 * 1024);  // 44-60 (overlays wqt)

    hipLaunchKernelGGL(prep_kernel, dim3(N3 / 64, 16), dim3(256), 0, stream,
                       Wq, Al, Bl, wqt_hi, wqt_lo, N3, 1);
    hipLaunchKernelGGL(prep_kernel, dim3(DD / 64, 16), dim3(256), 0, stream,
                       Wp, (const float*)nullptr, (const float*)nullptr,
                       wpt_hi, wpt_lo, DD, 0);
    hipLaunchKernelGGL(gemm3, dim3(N3 / 128, MR / 128), dim3(256), 0, stream,
                       x, wqt_hi, wqt_lo, bq, qkf, vbb, (float*)nullptr, N3, 0);
    hipLaunchKernelGGL(attn_mfma, dim3(SS / 128, HH, BB), dim3(256), 0, stream,
                       qkf, vbb, ctxf);
    hipLaunchKernelGGL(gemm3, dim3(DD / 128, MR / 128), dim3(256), 0, stream,
                       ctxf, wpt_hi, wpt_lo, bp, (float*)nullptr, (short*)nullptr,
                       (float*)d_out, DD, 1);
}

// Round 2
// 348.232 us; speedup vs baseline: 1.3577x; 1.0377x over previous
//
#include <hip/hip_runtime.h>
#include <hip/hip_bf16.h>

// B=2, S=2048, D=1024, H=16, HD=64, RANK=8, ALPHA=8. ALL I/O FP32.
// R14 = R13 with the GEMM path restructured (attn body untouched):
//  - split_x pre-splits x -> bf16 hi/lo ONCE (was: re-split per k-step per
//    column-block inside gemm3 = ~50 VALU/thread/k-step)
//  - attn epilogue writes ctx directly as bf16 hi/lo (same split2 of the
//    same fp32 value -> bit-identical numerics)
//  - all gemm operands stored TILE-MAJOR [panel][kchunk][q4][row128][8] so
//    gemm3 stages via linear global_load_lds_dwordx4 (m97 lever: no VALU,
//    no reg round-trip, LDS image identical to the proven fragment layout)
// ws (72 MB): qkf 0-32 | vbb 32-40 | wpt hi 40-42 lo 42-44 |
//             wqt hi 44-50 lo 50-56 | xhi 56-64 xlo 64-72 |
//             ctxhi 44-52 ctxlo 52-60 (overlay wqt/x, dead after QKV gemm).

#define BB    2
#define SS    2048
#define DD    1024
#define HH    16
#define HDIM  64
#define N3    3072
#define MR    4096

typedef short short8 __attribute__((ext_vector_type(8)));
typedef float f32x4 __attribute__((ext_vector_type(4)));

#define MFMA16(a, b, c) __builtin_amdgcn_mfma_f32_16x16x32_bf16((a), (b), (c), 0, 0, 0)

__device__ __forceinline__ float b2f(short s) {
    union { unsigned int u; float f; } c;
    c.u = ((unsigned int)(unsigned short)s) << 16;
    return c.f;
}
__device__ __forceinline__ short f2b(float f) {
    union { __hip_bfloat16 h; short s; } c;
    c.h = __float2bfloat16(f);
    return c.s;
}
struct HiLo { short hi, lo; };
__device__ __forceinline__ HiLo split2(float v) {
    HiLo r;
    r.hi = f2b(v);
    r.lo = f2b(v - b2f(r.hi));   // exact residual; next 8 mantissa bits
    return r;
}

__device__ __forceinline__ void gl_lds16(const void* g, void* l) {
    __builtin_amdgcn_global_load_lds(
        (const __attribute__((address_space(1))) void*)g,
        (__attribute__((address_space(3))) void*)l, 16, 0, 0);
}

// Tile-major offset for bf16 operand matrices consumed by gemm3:
// X[m][k] lives at ((m>>7)*32 + (k>>5))*4096 + ((k>>3)&3)*1024 + (m&127)*8 + (k&7)

// ---------------------------------------------------------------- split_x
// x fp32 [4096][1024] -> xhi/xlo bf16 tile-major. One block per (kchunk,panel).
__global__ __launch_bounds__(256) void split_x(const float* __restrict__ X,
                                               short* __restrict__ Xhi,
                                               short* __restrict__ Xlo) {
    int kc = blockIdx.x, p = blockIdx.y;
    int tid = threadIdx.x;
    int row = tid >> 1, half = tid & 1;
    const float* src = &X[((size_t)p * 128 + row) * 1024 + kc * 32 + half * 16];
    f32x4 v[4];
#pragma unroll
    for (int u = 0; u < 4; u++) v[u] = *(const f32x4*)(src + u * 4);
    size_t base = ((size_t)p * 32 + kc) * 4096 + (size_t)(half * 2) * 1024 + row * 8;
#pragma unroll
    for (int u = 0; u < 2; u++) {
        short8 h8, l8;
#pragma unroll
        for (int j = 0; j < 8; j++) {
            HiLo hl = split2(v[u * 2 + (j >> 2)][j & 3]);
            h8[j] = hl.hi; l8[j] = hl.lo;
        }
        *(short8*)&Xhi[base + u * 1024] = h8;
        *(short8*)&Xlo[base + u * 1024] = l8;
    }
}

// ---------------------------------------------------------------- prep
// Whi/Wlo = bf16split( W[k][n] + lora*8*sum_r A[k][r]*B[r][n] ), tile-major out.
__global__ __launch_bounds__(256) void prep_kernel(
    const float* __restrict__ W, const float* __restrict__ Al,
    const float* __restrict__ Bl, short* __restrict__ Whi,
    short* __restrict__ Wlo, int N, int lora)
{
    __shared__ float sw[64][68];
    __shared__ float sa[64][8];
    __shared__ float sb[8][64];
    int tid = threadIdx.x;
    int n0 = blockIdx.x * 64, k0 = blockIdx.y * 64;
#pragma unroll
    for (int p = 0; p < 4; p++) {
        int idx = p * 256 + tid;
        int kr = idx >> 4, ch = idx & 15;
        *(f32x4*)&sw[kr][ch * 4] = *(const f32x4*)&W[(size_t)(k0 + kr) * N + n0 + ch * 4];
    }
    if (lora) {
        if (tid < 64) {
#pragma unroll
            for (int r = 0; r < 8; r++) sa[tid][r] = Al[(k0 + tid) * 8 + r];
        } else if (tid < 128) {
            int c = tid - 64;
#pragma unroll
            for (int r = 0; r < 8; r++) sb[r][c] = Bl[(size_t)r * N + n0 + c];
        }
    }
    __syncthreads();
#pragma unroll
    for (int p = 0; p < 2; p++) {
        int idx = p * 256 + tid;
        int nr = idx >> 3, ch = idx & 7;
        short8 h8, l8;
#pragma unroll
        for (int j = 0; j < 8; j++) {
            int k = ch * 8 + j;
            float v = sw[k][nr];
            if (lora) {
                float a2 = 0.f;
#pragma unroll
                for (int r = 0; r < 8; r++) a2 += sa[k][r] * sb[r][nr];
                v += 8.0f * a2;
            }
            HiLo hl = split2(v);
            h8[j] = hl.hi;
            l8[j] = hl.lo;
        }
        int n = n0 + nr;
        int kchunk = (k0 >> 5) + (ch >> 2);
        size_t off = ((size_t)(n >> 7) * 32 + kchunk) * 4096 +
                     (size_t)(ch & 3) * 1024 + (n & 127) * 8;
        *(short8*)&Whi[off] = h8;
        *(short8*)&Wlo[off] = l8;
    }
}

// ---------------------------------------------------------------- gemm3
// C[m][n] = sum_k (Ahi+Alo)[m][k]*(Bhi+Blo)[n][k] (3-term hi/lo) + bias[n].
// All operands bf16 tile-major; staging = 8 linear global_load_lds dwordx4
// per k-step (m97 structure). 128x128 tile, 4 waves, BK=32.
__global__ __launch_bounds__(256) void gemm3(
    const short* __restrict__ Ahi, const short* __restrict__ Alo,
    const short* __restrict__ Bhi, const short* __restrict__ Blo,
    const float* __restrict__ bias,
    float* __restrict__ outqk, short* __restrict__ outv,
    float* __restrict__ outf32, int N, int mode)
{
    __shared__ short lds[4][4][128][8];   // arr(Ah,Al,Bh,Bl) x [q4][row][j]
    int tid = threadIdx.x;
    int wav = tid >> 6, lane = tid & 63;
    int l15 = lane & 15, q4 = lane >> 4;
    int wm = wav & 1, wn = wav >> 1;
    int n0 = blockIdx.x * 128, m0 = blockIdx.y * 128;

    const short* ga_h = Ahi + ((size_t)blockIdx.y * 32) * 4096 + tid * 8;
    const short* ga_l = Alo + ((size_t)blockIdx.y * 32) * 4096 + tid * 8;
    const short* gb_h = Bhi + ((size_t)blockIdx.x * 32) * 4096 + tid * 8;
    const short* gb_l = Blo + ((size_t)blockIdx.x * 32) * 4096 + tid * 8;
    short* l0 = &lds[0][0][0][0] + tid * 8;

    f32x4 acc[4][4] = {};

    for (int kc = 0; kc < 32; ++kc) {
        __syncthreads();               // previous iteration's frag reads done
        int koff = kc * 4096;
        gl_lds16(ga_h + koff,        l0);
        gl_lds16(ga_h + koff + 2048, l0 + 2048);
        gl_lds16(ga_l + koff,        l0 + 4096);
        gl_lds16(ga_l + koff + 2048, l0 + 6144);
        gl_lds16(gb_h + koff,        l0 + 8192);
        gl_lds16(gb_h + koff + 2048, l0 + 10240);
        gl_lds16(gb_l + koff,        l0 + 12288);
        gl_lds16(gb_l + koff + 2048, l0 + 14336);
        __syncthreads();               // vmcnt(0) drain: LDS tile ready
        short8 ah[4], al_[4], bh[4], bl[4];
#pragma unroll
        for (int i = 0; i < 4; i++) {
            ah[i]  = *(short8*)&lds[0][q4][wm * 64 + i * 16 + l15][0];
            al_[i] = *(short8*)&lds[1][q4][wm * 64 + i * 16 + l15][0];
            bh[i]  = *(short8*)&lds[2][q4][wn * 64 + i * 16 + l15][0];
            bl[i]  = *(short8*)&lds[3][q4][wn * 64 + i * 16 + l15][0];
        }
#pragma unroll
        for (int mi = 0; mi < 4; mi++)
#pragma unroll
            for (int ni = 0; ni < 4; ni++) {
                acc[mi][ni] = MFMA16(ah[mi], bh[ni], acc[mi][ni]);
                acc[mi][ni] = MFMA16(ah[mi], bl[ni], acc[mi][ni]);
                acc[mi][ni] = MFMA16(al_[mi], bh[ni], acc[mi][ni]);
            }
    }
#pragma unroll
    for (int ni = 0; ni < 4; ni++) {
        int n = n0 + wn * 64 + ni * 16 + l15;
        float bv = bias[n];
#pragma unroll
        for (int mi = 0; mi < 4; mi++) {
            int mbase = m0 + wm * 64 + mi * 16 + q4 * 4;
#pragma unroll
            for (int r = 0; r < 4; r++) {
                int m = mbase + r;
                float v = acc[mi][ni][r] + bv;
                if (mode == 0) {
                    if (n < 2048) outqk[(size_t)m * 2048 + n] = v;
                    else          outv[(size_t)m * 1024 + (n - 2048)] = f2b(v);
                } else {
                    outf32[(size_t)m * 1024 + n] = v;
                }
            }
        }
    }
}

// ---------------------------------------------------------------- attn_mfma
// grid (S/128, H, B) = 512 blocks; block x processes q-tiles {31-x, x}
// (33 chunks each). Double-buffered K/V LDS, ONE barrier per 64-key chunk,
// next-chunk global loads issued before current compute. Epilogue writes
// ctx as bf16 hi/lo tile-major (feeds proj gemm directly).
__global__ __launch_bounds__(256) void attn_mfma(const float* __restrict__ qk,
                                                 const short* __restrict__ vb,
                                                 short* __restrict__ ctxhi,
                                                 short* __restrict__ ctxlo) {
    __shared__ short Kh[2][8][64][8];      // [buf][hd-octet][key][j]  hi
    __shared__ short Kl[2][8][64][8];      //                          lo
    __shared__ short Vt[2][8][64][8];      // [buf][key-octet][hd][key&7]
    __shared__ short Pt[4][8][17][8];      // [wave][key-octet][qrow(+pad)][j]

    int h = blockIdx.y, b = blockIdx.z;
    int tid = threadIdx.x, wav = tid >> 6, lane = tid & 63;
    int l15 = lane & 15, q4 = lane >> 4;
    int skey = tid >> 3, sch = tid & 7;          // K staging coords
    const float* bqk = qk + (size_t)b * SS * 2048;
    const short* bv  = vb + (size_t)b * SS * 1024;

    // prefetch registers (chunk c+1 lives here during chunk c's compute)
    f32x4 ka[2][2];
    short vr[16];

#define LOADKV(c)                                                               \
    {                                                                           \
        int kk_ = (c) * 64;                                                     \
        const float* ks_ = &bqk[(size_t)(kk_ + skey) * 2048 + 1024 + h * 64 + sch * 8]; \
        ka[0][0] = *(const f32x4*)ks_;                                          \
        ka[0][1] = *(const f32x4*)(ks_ + 4);                                    \
        ka[1][0] = *(const f32x4*)(ks_ + 32 * 2048);                            \
        ka[1][1] = *(const f32x4*)(ks_ + 32 * 2048 + 4);                        \
        const short* vs_ = &bv[(size_t)(kk_ + wav * 16) * 1024 + h * 64 + lane]; \
        _Pragma("unroll") for (int j_ = 0; j_ < 16; ++j_) vr[j_] = vs_[(size_t)j_ * 1024]; \
    }

#define STAGEKV(buf)                                                            \
    {                                                                           \
        _Pragma("unroll") for (int p_ = 0; p_ < 2; ++p_) {                      \
            short8 h8_, l8_;                                                    \
            _Pragma("unroll") for (int j_ = 0; j_ < 4; ++j_) {                  \
                HiLo u_ = split2(ka[p_][0][j_]); h8_[j_] = u_.hi; l8_[j_] = u_.lo; \
                HiLo w_ = split2(ka[p_][1][j_]); h8_[4 + j_] = w_.hi; l8_[4 + j_] = w_.lo; \
            }                                                                   \
            int key_ = p_ * 32 + skey;                                          \
            *(short8*)&Kh[buf][sch][key_][0] = h8_;                             \
            *(short8*)&Kl[buf][sch][key_][0] = l8_;                             \
        }                                                                       \
        short8 v0_, v1_;                                                        \
        _Pragma("unroll") for (int j_ = 0; j_ < 8; ++j_) { v0_[j_] = vr[j_]; v1_[j_] = vr[8 + j_]; } \
        *(short8*)&Vt[buf][wav * 2][lane][0] = v0_;                             \
        *(short8*)&Vt[buf][wav * 2 + 1][lane][0] = v1_;                         \
    }

    for (int t = 0; t < 2; ++t) {
        int qt = t ? (int)blockIdx.x : 31 - (int)blockIdx.x;
        int qb = qt * 64;

        size_t qoff = (size_t)(qb + wav * 16 + l15) * 2048 + h * 64;
        short8 q0h, q0l, q1h, q1l;
        {
            f32x4 a0 = *(const f32x4*)&bqk[qoff + q4 * 8];
            f32x4 a1 = *(const f32x4*)&bqk[qoff + q4 * 8 + 4];
            f32x4 c0 = *(const f32x4*)&bqk[qoff + 32 + q4 * 8];
            f32x4 c1 = *(const f32x4*)&bqk[qoff + 32 + q4 * 8 + 4];
#pragma unroll
            for (int j = 0; j < 4; j++) {
                HiLo u = split2(a0[j]); q0h[j] = u.hi; q0l[j] = u.lo;
                HiLo v = split2(a1[j]); q0h[4 + j] = v.hi; q0l[4 + j] = v.lo;
                HiLo w = split2(c0[j]); q1h[j] = w.hi; q1l[j] = w.lo;
                HiLo z = split2(c1[j]); q1h[4 + j] = z.hi; q1l[4 + j] = z.lo;
            }
        }

        f32x4 o[4] = {};
        float m[4]  = {-1e30f, -1e30f, -1e30f, -1e30f};
        float lsum[4] = {0.f, 0.f, 0.f, 0.f};
        int nch = qt + 1;

        LOADKV(0);
        STAGEKV(0);
        __syncthreads();

        for (int c = 0; c < nch; ++c) {
            int cur = c & 1;
            int k0 = c * 64;

            if (c + 1 < nch) LOADKV(c + 1);

            // ---- scores: 4 groups of 16 keys, 6 MFMAs each (hi/lo)
            f32x4 s[4];
#pragma unroll
            for (int g = 0; g < 4; g++) {
                short8 k0h_ = *(short8*)&Kh[cur][q4][g * 16 + l15][0];
                short8 k0l_ = *(short8*)&Kl[cur][q4][g * 16 + l15][0];
                short8 k1h_ = *(short8*)&Kh[cur][4 + q4][g * 16 + l15][0];
                short8 k1l_ = *(short8*)&Kl[cur][4 + q4][g * 16 + l15][0];
                f32x4 acc = {};
                acc = MFMA16(q0h, k0h_, acc);
                acc = MFMA16(q0h, k0l_, acc);
                acc = MFMA16(q0l, k0h_, acc);
                acc = MFMA16(q1h, k1h_, acc);
                acc = MFMA16(q1h, k1l_, acc);
                acc = MFMA16(q1l, k1h_, acc);
                s[g] = acc;
            }

            // ---- online softmax per row r (C layout: col=l15 key, row=q4*4+r)
            float alpha[4];
#pragma unroll
            for (int r = 0; r < 4; r++) {
                int q = qb + wav * 16 + q4 * 4 + r;
                float a[4];
#pragma unroll
                for (int g = 0; g < 4; g++) {
                    int key = k0 + g * 16 + l15;
                    a[g] = (key <= q) ? s[g][r] * 0.125f : -1e30f;
                }
                float mx = fmaxf(fmaxf(a[0], a[1]), fmaxf(a[2], a[3]));
                mx = fmaxf(mx, __shfl_xor(mx, 1, 64));
                mx = fmaxf(mx, __shfl_xor(mx, 2, 64));
                mx = fmaxf(mx, __shfl_xor(mx, 4, 64));
                mx = fmaxf(mx, __shfl_xor(mx, 8, 64));
                float mn = fmaxf(m[r], mx);
                float p0 = __expf(a[0] - mn), p1 = __expf(a[1] - mn);
                float p2 = __expf(a[2] - mn), p3 = __expf(a[3] - mn);
                float sm = p0 + p1 + p2 + p3;
                sm += __shfl_xor(sm, 1, 64);
                sm += __shfl_xor(sm, 2, 64);
                sm += __shfl_xor(sm, 4, 64);
                sm += __shfl_xor(sm, 8, 64);
                alpha[r] = __expf(m[r] - mn);
                m[r] = mn;
                lsum[r] = lsum[r] * alpha[r] + sm;
                int kq = (l15 >> 3), j = l15 & 7, row = q4 * 4 + r;
                Pt[wav][0 + kq][row][j] = f2b(p0);
                Pt[wav][2 + kq][row][j] = f2b(p1);
                Pt[wav][4 + kq][row][j] = f2b(p2);
                Pt[wav][6 + kq][row][j] = f2b(p3);
            }
            // Pt per-wave; Vt[cur] published by last iteration's barrier.

            short8 pf0 = *(short8*)&Pt[wav][q4][l15][0];
            short8 pf1 = *(short8*)&Pt[wav][4 + q4][l15][0];
#pragma unroll
            for (int gg = 0; gg < 4; gg++) {
                short8 vf0 = *(short8*)&Vt[cur][q4][gg * 16 + l15][0];
                short8 vf1 = *(short8*)&Vt[cur][4 + q4][gg * 16 + l15][0];
                f32x4 tt = o[gg];
                tt[0] *= alpha[0]; tt[1] *= alpha[1]; tt[2] *= alpha[2]; tt[3] *= alpha[3];
                tt = MFMA16(pf0, vf0, tt);
                tt = MFMA16(pf1, vf1, tt);
                o[gg] = tt;
            }

            if (c + 1 < nch) STAGEKV(cur ^ 1);
            __syncthreads();
        }

#pragma unroll
        for (int gg = 0; gg < 4; gg++)
#pragma unroll
            for (int r = 0; r < 4; r++) {
                int q = qb + wav * 16 + q4 * 4 + r;
                int mrow = b * SS + q;
                int k = h * 64 + gg * 16 + l15;
                HiLo hl = split2(o[gg][r] / lsum[r]);
                size_t off = ((size_t)(mrow >> 7) * 32 + (k >> 5)) * 4096 +
                             (size_t)((k >> 3) & 3) * 1024 + (mrow & 127) * 8 + (k & 7);
                ctxhi[off] = hl.hi;
                ctxlo[off] = hl.lo;
            }
    }
#undef LOADKV
#undef STAGEKV
}

extern "C" void kernel_launch(void* const* d_in, const int* in_sizes, int n_in,
                              void* d_out, int out_size, void* d_ws, size_t ws_size,
                              hipStream_t stream) {
    const float* x  = (const float*)d_in[0];
    const float* Wq = (const float*)d_in[1];
    const float* bq = (const float*)d_in[2];
    const float* Al = (const float*)d_in[3];
    const float* Bl = (const float*)d_in[4];
    const float* Wp = (const float*)d_in[5];
    const float* bp = (const float*)d_in[6];

    char* ws = (char*)d_ws;
    float* qkf    = (float*)(ws);                             // 0-32 MB
    short* vbb    = (short*)(ws + (size_t)32 * 1024 * 1024);  // 32-40
    short* wpt_hi = (short*)(ws + (size_t)40 * 1024 * 1024);  // 40-42
    short* wpt_lo = (short*)(ws + (size_t)42 * 1024 * 1024);  // 42-44
    short* wqt_hi = (short*)(ws + (size_t)44 * 1024 * 1024);  // 44-50
    short* wqt_lo = (short*)(ws + (size_t)50 * 1024 * 1024);  // 50-56
    short* xhi    = (short*)(ws + (size_t)56 * 1024 * 1024);  // 56-64
    short* xlo    = (short*)(ws + (size_t)64 * 1024 * 1024);  // 64-72
    short* ctxhi  = (short*)(ws + (size_t)44 * 1024 * 1024);  // 44-52 (overlays dead wqt_hi)
    short* ctxlo  = (short*)(ws + (size_t)52 * 1024 * 1024);  // 52-60 (overlays dead wqt_lo/xhi)

    hipLaunchKernelGGL(split_x, dim3(32, 32), dim3(256), 0, stream, x, xhi, xlo);
    hipLaunchKernelGGL(prep_kernel, dim3(N3 / 64, 16), dim3(256), 0, stream,
                       Wq, Al, Bl, wqt_hi, wqt_lo, N3, 1);
    hipLaunchKernelGGL(prep_kernel, dim3(DD / 64, 16), dim3(256), 0, stream,
                       Wp, (const float*)nullptr, (const float*)nullptr,
                       wpt_hi, wpt_lo, DD, 0);
    hipLaunchKernelGGL(gemm3, dim3(N3 / 128, MR / 128), dim3(256), 0, stream,
                       xhi, xlo, wqt_hi, wqt_lo, bq, qkf, vbb, (float*)nullptr, N3, 0);
    hipLaunchKernelGGL(attn_mfma, dim3(SS / 128, HH, BB), dim3(256), 0, stream,
                       qkf, vbb, ctxhi, ctxlo);
    hipLaunchKernelGGL(gemm3, dim3(DD / 128, MR / 128), dim3(256), 0, stream,
                       ctxhi, ctxlo, wpt_hi, wpt_lo, bp, (float*)nullptr, (short*)nullptr,
                       (float*)d_out, DD, 1);
}

// Round 3
// 319.921 us; speedup vs baseline: 1.4779x; 1.0885x over previous
//
#include <hip/hip_runtime.h>
#include <hip/hip_bf16.h>

// B=2, S=2048, D=1024, H=16, HD=64, RANK=8, ALPHA=8. ALL I/O FP32.
// R15 = R14 with the attn staging VALU eliminated:
//  - QKV gemm3 epilogue now emits: Q pre-scaled (x0.125, exact pow2) fp32;
//    K pre-split bf16 hi/lo in attn-LDS layout [hd>>3][key][hd&7];
//    V bf16 in attn-LDS layout [key>>3][hd][key&7] -- per (b,h,chunk) block.
//  - attn stages K/V via 6 linear global_load_lds_dwordx4 per 64-key chunk
//    (zero VALU, zero reg round-trip; was ~16 split2 + 16 scalar V loads).
//  - causal mask applied only on the diagonal chunk (c == qt).
//  All math bit-identical to R14 (same split2 of same fp32; pow2 scale
//  commutes exactly) -> absmax unchanged.
// ws (72 MB): qf 0-16 | khi 16-24 | klo 24-32 | vt 32-40 |
//             wpt hi 40-42 lo 42-44 | wqt hi 44-50 lo 50-56 |
//             xhi 56-64 xlo 64-72 | ctxhi 44-52 ctxlo 52-60 (overlay dead).

#define BB    2
#define SS    2048
#define DD    1024
#define HH    16
#define HDIM  64
#define N3    3072
#define MR    4096

typedef short short8 __attribute__((ext_vector_type(8)));
typedef float f32x4 __attribute__((ext_vector_type(4)));

#define MFMA16(a, b, c) __builtin_amdgcn_mfma_f32_16x16x32_bf16((a), (b), (c), 0, 0, 0)

__device__ __forceinline__ float b2f(short s) {
    union { unsigned int u; float f; } c;
    c.u = ((unsigned int)(unsigned short)s) << 16;
    return c.f;
}
__device__ __forceinline__ short f2b(float f) {
    union { __hip_bfloat16 h; short s; } c;
    c.h = __float2bfloat16(f);
    return c.s;
}
struct HiLo { short hi, lo; };
__device__ __forceinline__ HiLo split2(float v) {
    HiLo r;
    r.hi = f2b(v);
    r.lo = f2b(v - b2f(r.hi));   // exact residual; next 8 mantissa bits
    return r;
}

__device__ __forceinline__ void gl_lds16(const void* g, void* l) {
    __builtin_amdgcn_global_load_lds(
        (const __attribute__((address_space(1))) void*)g,
        (__attribute__((address_space(3))) void*)l, 16, 0, 0);
}

// Tile-major offset for bf16 operand matrices consumed by gemm3:
// X[m][k] lives at ((m>>7)*32 + (k>>5))*4096 + ((k>>3)&3)*1024 + (m&127)*8 + (k&7)

// ---------------------------------------------------------------- split_x
// x fp32 [4096][1024] -> xhi/xlo bf16 tile-major. One block per (kchunk,panel).
__global__ __launch_bounds__(256) void split_x(const float* __restrict__ X,
                                               short* __restrict__ Xhi,
                                               short* __restrict__ Xlo) {
    int kc = blockIdx.x, p = blockIdx.y;
    int tid = threadIdx.x;
    int row = tid >> 1, half = tid & 1;
    const float* src = &X[((size_t)p * 128 + row) * 1024 + kc * 32 + half * 16];
    f32x4 v[4];
#pragma unroll
    for (int u = 0; u < 4; u++) v[u] = *(const f32x4*)(src + u * 4);
    size_t base = ((size_t)p * 32 + kc) * 4096 + (size_t)(half * 2) * 1024 + row * 8;
#pragma unroll
    for (int u = 0; u < 2; u++) {
        short8 h8, l8;
#pragma unroll
        for (int j = 0; j < 8; j++) {
            HiLo hl = split2(v[u * 2 + (j >> 2)][j & 3]);
            h8[j] = hl.hi; l8[j] = hl.lo;
        }
        *(short8*)&Xhi[base + u * 1024] = h8;
        *(short8*)&Xlo[base + u * 1024] = l8;
    }
}

// ---------------------------------------------------------------- prep
// Whi/Wlo = bf16split( W[k][n] + lora*8*sum_r A[k][r]*B[r][n] ), tile-major out.
__global__ __launch_bounds__(256) void prep_kernel(
    const float* __restrict__ W, const float* __restrict__ Al,
    const float* __restrict__ Bl, short* __restrict__ Whi,
    short* __restrict__ Wlo, int N, int lora)
{
    __shared__ float sw[64][68];
    __shared__ float sa[64][8];
    __shared__ float sb[8][64];
    int tid = threadIdx.x;
    int n0 = blockIdx.x * 64, k0 = blockIdx.y * 64;
#pragma unroll
    for (int p = 0; p < 4; p++) {
        int idx = p * 256 + tid;
        int kr = idx >> 4, ch = idx & 15;
        *(f32x4*)&sw[kr][ch * 4] = *(const f32x4*)&W[(size_t)(k0 + kr) * N + n0 + ch * 4];
    }
    if (lora) {
        if (tid < 64) {
#pragma unroll
            for (int r = 0; r < 8; r++) sa[tid][r] = Al[(k0 + tid) * 8 + r];
        } else if (tid < 128) {
            int c = tid - 64;
#pragma unroll
            for (int r = 0; r < 8; r++) sb[r][c] = Bl[(size_t)r * N + n0 + c];
        }
    }
    __syncthreads();
#pragma unroll
    for (int p = 0; p < 2; p++) {
        int idx = p * 256 + tid;
        int nr = idx >> 3, ch = idx & 7;
        short8 h8, l8;
#pragma unroll
        for (int j = 0; j < 8; j++) {
            int k = ch * 8 + j;
            float v = sw[k][nr];
            if (lora) {
                float a2 = 0.f;
#pragma unroll
                for (int r = 0; r < 8; r++) a2 += sa[k][r] * sb[r][nr];
                v += 8.0f * a2;
            }
            HiLo hl = split2(v);
            h8[j] = hl.hi;
            l8[j] = hl.lo;
        }
        int n = n0 + nr;
        int kchunk = (k0 >> 5) + (ch >> 2);
        size_t off = ((size_t)(n >> 7) * 32 + kchunk) * 4096 +
                     (size_t)(ch & 3) * 1024 + (n & 127) * 8;
        *(short8*)&Whi[off] = h8;
        *(short8*)&Wlo[off] = l8;
    }
}

// ---------------------------------------------------------------- gemm3
// C[m][n] = sum_k (Ahi+Alo)[m][k]*(Bhi+Blo)[n][k] (3-term hi/lo) + bias[n].
// mode 0 (QKV): n<1024 -> qf = v*0.125 (fp32); 1024..2047 -> khi/klo bf16
// split in attn-LDS layout; >=2048 -> vt bf16 in attn-LDS layout.
// mode 1 (proj): outf32 row-major.
__global__ __launch_bounds__(256) void gemm3(
    const short* __restrict__ Ahi, const short* __restrict__ Alo,
    const short* __restrict__ Bhi, const short* __restrict__ Blo,
    const float* __restrict__ bias,
    float* __restrict__ qf, short* __restrict__ khi, short* __restrict__ klo,
    short* __restrict__ vt, float* __restrict__ outf32, int N, int mode)
{
    __shared__ short lds[4][4][128][8];   // arr(Ah,Al,Bh,Bl) x [q4][row][j]
    int tid = threadIdx.x;
    int wav = tid >> 6, lane = tid & 63;
    int l15 = lane & 15, q4 = lane >> 4;
    int wm = wav & 1, wn = wav >> 1;
    int n0 = blockIdx.x * 128, m0 = blockIdx.y * 128;

    const short* ga_h = Ahi + ((size_t)blockIdx.y * 32) * 4096 + tid * 8;
    const short* ga_l = Alo + ((size_t)blockIdx.y * 32) * 4096 + tid * 8;
    const short* gb_h = Bhi + ((size_t)blockIdx.x * 32) * 4096 + tid * 8;
    const short* gb_l = Blo + ((size_t)blockIdx.x * 32) * 4096 + tid * 8;
    short* l0 = &lds[0][0][0][0] + tid * 8;

    f32x4 acc[4][4] = {};

    for (int kc = 0; kc < 32; ++kc) {
        __syncthreads();               // previous iteration's frag reads done
        int koff = kc * 4096;
        gl_lds16(ga_h + koff,        l0);
        gl_lds16(ga_h + koff + 2048, l0 + 2048);
        gl_lds16(ga_l + koff,        l0 + 4096);
        gl_lds16(ga_l + koff + 2048, l0 + 6144);
        gl_lds16(gb_h + koff,        l0 + 8192);
        gl_lds16(gb_h + koff + 2048, l0 + 10240);
        gl_lds16(gb_l + koff,        l0 + 12288);
        gl_lds16(gb_l + koff + 2048, l0 + 14336);
        __syncthreads();               // vmcnt(0) drain: LDS tile ready
        short8 ah[4], al_[4], bh[4], bl[4];
#pragma unroll
        for (int i = 0; i < 4; i++) {
            ah[i]  = *(short8*)&lds[0][q4][wm * 64 + i * 16 + l15][0];
            al_[i] = *(short8*)&lds[1][q4][wm * 64 + i * 16 + l15][0];
            bh[i]  = *(short8*)&lds[2][q4][wn * 64 + i * 16 + l15][0];
            bl[i]  = *(short8*)&lds[3][q4][wn * 64 + i * 16 + l15][0];
        }
#pragma unroll
        for (int mi = 0; mi < 4; mi++)
#pragma unroll
            for (int ni = 0; ni < 4; ni++) {
                acc[mi][ni] = MFMA16(ah[mi], bh[ni], acc[mi][ni]);
                acc[mi][ni] = MFMA16(ah[mi], bl[ni], acc[mi][ni]);
                acc[mi][ni] = MFMA16(al_[mi], bh[ni], acc[mi][ni]);
            }
    }
#pragma unroll
    for (int ni = 0; ni < 4; ni++) {
        int n = n0 + wn * 64 + ni * 16 + l15;
        float bv = bias[n];
#pragma unroll
        for (int mi = 0; mi < 4; mi++) {
            int mbase = m0 + wm * 64 + mi * 16 + q4 * 4;
#pragma unroll
            for (int r = 0; r < 4; r++) {
                int m = mbase + r;
                float v = acc[mi][ni][r] + bv;
                if (mode != 0) {
                    outf32[(size_t)m * 1024 + n] = v;
                } else if (n0 < 1024) {
                    qf[(size_t)m * 1024 + n] = v * 0.125f;   // pow2: exact
                } else if (n0 < 2048) {
                    int kk = n - 1024, hh = kk >> 6, hd = kk & 63;
                    int bb_ = m >> 11, s = m & 2047;
                    size_t base = ((size_t)((bb_ << 4) + hh) * 32 + (s >> 6)) * 4096
                                  + (size_t)(hd >> 3) * 512 + (s & 63) * 8 + (hd & 7);
                    HiLo hl = split2(v);
                    khi[base] = hl.hi;
                    klo[base] = hl.lo;
                } else {
                    int kk = n - 2048, hh = kk >> 6, hd = kk & 63;
                    int bb_ = m >> 11, s = m & 2047;
                    size_t base = ((size_t)((bb_ << 4) + hh) * 32 + (s >> 6)) * 4096
                                  + (size_t)((s >> 3) & 7) * 512 + hd * 8 + (s & 7);
                    vt[base] = f2b(v);
                }
            }
        }
    }
}

// ---------------------------------------------------------------- attn_mfma
// grid (S/128, H, B) = 512 blocks; block x processes q-tiles {31-x, x}.
// K/V staged via 6 linear global_load_lds_dwordx4 per chunk into
// double-buffered LDS (zero staging VALU), ONE barrier per chunk.
// Mask only on diagonal chunk; Q pre-scaled by 0.125 upstream.
__global__ __launch_bounds__(256) void attn_mfma(const float* __restrict__ qf,
                                                 const short* __restrict__ khi,
                                                 const short* __restrict__ klo,
                                                 const short* __restrict__ vtg,
                                                 short* __restrict__ ctxhi,
                                                 short* __restrict__ ctxlo) {
    __shared__ short KhL[2][4096];      // [buf][(hd>>3)*512 + key*8 + (hd&7)]
    __shared__ short KlL[2][4096];
    __shared__ short VtL[2][4096];      // [buf][(key>>3)*512 + hd*8 + (key&7)]
    __shared__ short Pt[4][8][17][8];   // [wave][key-octet][qrow(+pad)][j]

    int h = blockIdx.y, b = blockIdx.z;
    int tid = threadIdx.x, wav = tid >> 6, lane = tid & 63;
    int l15 = lane & 15, q4 = lane >> 4;
    const float* bq = qf + (size_t)b * SS * 1024;
    size_t hb = (size_t)((b * 16 + h) * 32) * 4096;
    const short* gkh = khi + hb;
    const short* gkl = klo + hb;
    const short* gvt = vtg + hb;
    int t8 = tid * 8;

#define ISSUE(c, buf)                                                   \
    {                                                                   \
        size_t co_ = (size_t)(c) * 4096 + t8;                           \
        gl_lds16(gkh + co_,        &KhL[buf][t8]);                      \
        gl_lds16(gkh + co_ + 2048, &KhL[buf][t8 + 2048]);               \
        gl_lds16(gkl + co_,        &KlL[buf][t8]);                      \
        gl_lds16(gkl + co_ + 2048, &KlL[buf][t8 + 2048]);               \
        gl_lds16(gvt + co_,        &VtL[buf][t8]);                      \
        gl_lds16(gvt + co_ + 2048, &VtL[buf][t8 + 2048]);               \
    }

    for (int t = 0; t < 2; ++t) {
        int qt = t ? (int)blockIdx.x : 31 - (int)blockIdx.x;
        int qb = qt * 64;

        // Q fragments (values pre-scaled by 0.125 in gemm3 epilogue)
        size_t qoff = (size_t)(qb + wav * 16 + l15) * 1024 + h * 64;
        short8 q0h, q0l, q1h, q1l;
        {
            f32x4 a0 = *(const f32x4*)&bq[qoff + q4 * 8];
            f32x4 a1 = *(const f32x4*)&bq[qoff + q4 * 8 + 4];
            f32x4 c0 = *(const f32x4*)&bq[qoff + 32 + q4 * 8];
            f32x4 c1 = *(const f32x4*)&bq[qoff + 32 + q4 * 8 + 4];
#pragma unroll
            for (int j = 0; j < 4; j++) {
                HiLo u = split2(a0[j]); q0h[j] = u.hi; q0l[j] = u.lo;
                HiLo v = split2(a1[j]); q0h[4 + j] = v.hi; q0l[4 + j] = v.lo;
                HiLo w = split2(c0[j]); q1h[j] = w.hi; q1l[j] = w.lo;
                HiLo z = split2(c1[j]); q1h[4 + j] = z.hi; q1l[4 + j] = z.lo;
            }
        }

        f32x4 o[4] = {};
        float m[4]  = {-1e30f, -1e30f, -1e30f, -1e30f};
        float lsum[4] = {0.f, 0.f, 0.f, 0.f};
        int nch = qt + 1;

        ISSUE(0, 0);
        __syncthreads();    // implicit vmcnt(0): chunk 0 staged

        for (int c = 0; c < nch; ++c) {
            int cur = c & 1;
            int k0 = c * 64;

            if (c + 1 < nch) ISSUE(c + 1, cur ^ 1);

            // ---- scores: 4 groups of 16 keys, 6 MFMAs each (hi/lo)
            f32x4 s[4];
#pragma unroll
            for (int g = 0; g < 4; g++) {
                int ko = (g * 16 + l15) * 8;
                short8 k0h_ = *(short8*)&KhL[cur][q4 * 512 + ko];
                short8 k0l_ = *(short8*)&KlL[cur][q4 * 512 + ko];
                short8 k1h_ = *(short8*)&KhL[cur][(4 + q4) * 512 + ko];
                short8 k1l_ = *(short8*)&KlL[cur][(4 + q4) * 512 + ko];
                f32x4 acc = {};
                acc = MFMA16(q0h, k0h_, acc);
                acc = MFMA16(q0h, k0l_, acc);
                acc = MFMA16(q0l, k0h_, acc);
                acc = MFMA16(q1h, k1h_, acc);
                acc = MFMA16(q1h, k1l_, acc);
                acc = MFMA16(q1l, k1h_, acc);
                s[g] = acc;
            }

            // ---- online softmax per row r (C layout: col=l15 key, row=q4*4+r)
            float alpha[4];
#pragma unroll
            for (int r = 0; r < 4; r++) {
                float a[4];
#pragma unroll
                for (int g = 0; g < 4; g++) a[g] = s[g][r];
                if (c == qt) {            // diagonal chunk: causal mask
                    int q = qb + wav * 16 + q4 * 4 + r;
#pragma unroll
                    for (int g = 0; g < 4; g++) {
                        int key = k0 + g * 16 + l15;
                        if (key > q) a[g] = -1e30f;
                    }
                }
                float mx = fmaxf(fmaxf(a[0], a[1]), fmaxf(a[2], a[3]));
                mx = fmaxf(mx, __shfl_xor(mx, 1, 64));
                mx = fmaxf(mx, __shfl_xor(mx, 2, 64));
                mx = fmaxf(mx, __shfl_xor(mx, 4, 64));
                mx = fmaxf(mx, __shfl_xor(mx, 8, 64));
                float mn = fmaxf(m[r], mx);
                float p0 = __expf(a[0] - mn), p1 = __expf(a[1] - mn);
                float p2 = __expf(a[2] - mn), p3 = __expf(a[3] - mn);
                float sm = p0 + p1 + p2 + p3;
                sm += __shfl_xor(sm, 1, 64);
                sm += __shfl_xor(sm, 2, 64);
                sm += __shfl_xor(sm, 4, 64);
                sm += __shfl_xor(sm, 8, 64);
                alpha[r] = __expf(m[r] - mn);
                m[r] = mn;
                lsum[r] = lsum[r] * alpha[r] + sm;
                int kq = (l15 >> 3), j = l15 & 7, row = q4 * 4 + r;
                Pt[wav][0 + kq][row][j] = f2b(p0);
                Pt[wav][2 + kq][row][j] = f2b(p1);
                Pt[wav][4 + kq][row][j] = f2b(p2);
                Pt[wav][6 + kq][row][j] = f2b(p3);
            }
            // Pt per-wave; VtL[cur] published by last iteration's barrier.

            short8 pf0 = *(short8*)&Pt[wav][q4][l15][0];
            short8 pf1 = *(short8*)&Pt[wav][4 + q4][l15][0];
#pragma unroll
            for (int gg = 0; gg < 4; gg++) {
                int vo = (gg * 16 + l15) * 8;
                short8 vf0 = *(short8*)&VtL[cur][q4 * 512 + vo];
                short8 vf1 = *(short8*)&VtL[cur][(4 + q4) * 512 + vo];
                f32x4 tt = o[gg];
                tt[0] *= alpha[0]; tt[1] *= alpha[1]; tt[2] *= alpha[2]; tt[3] *= alpha[3];
                tt = MFMA16(pf0, vf0, tt);
                tt = MFMA16(pf1, vf1, tt);
                o[gg] = tt;
            }

            __syncthreads();   // drains next-chunk gl_lds; orders buffer reuse
        }

#pragma unroll
        for (int gg = 0; gg < 4; gg++)
#pragma unroll
            for (int r = 0; r < 4; r++) {
                int q = qb + wav * 16 + q4 * 4 + r;
                int mrow = b * SS + q;
                int k = h * 64 + gg * 16 + l15;
                HiLo hl = split2(o[gg][r] / lsum[r]);
                size_t off = ((size_t)(mrow >> 7) * 32 + (k >> 5)) * 4096 +
                             (size_t)((k >> 3) & 3) * 1024 + (mrow & 127) * 8 + (k & 7);
                ctxhi[off] = hl.hi;
                ctxlo[off] = hl.lo;
            }
    }
#undef ISSUE
}

extern "C" void kernel_launch(void* const* d_in, const int* in_sizes, int n_in,
                              void* d_out, int out_size, void* d_ws, size_t ws_size,
                              hipStream_t stream) {
    const float* x  = (const float*)d_in[0];
    const float* Wq = (const float*)d_in[1];
    const float* bq = (const float*)d_in[2];
    const float* Al = (const float*)d_in[3];
    const float* Bl = (const float*)d_in[4];
    const float* Wp = (const float*)d_in[5];
    const float* bp = (const float*)d_in[6];

    char* ws = (char*)d_ws;
    float* qf     = (float*)(ws);                             // 0-16 MB
    short* khi    = (short*)(ws + (size_t)16 * 1024 * 1024);  // 16-24
    short* klo    = (short*)(ws + (size_t)24 * 1024 * 1024);  // 24-32
    short* vt     = (short*)(ws + (size_t)32 * 1024 * 1024);  // 32-40
    short* wpt_hi = (short*)(ws + (size_t)40 * 1024 * 1024);  // 40-42
    short* wpt_lo = (short*)(ws + (size_t)42 * 1024 * 1024);  // 42-44
    short* wqt_hi = (short*)(ws + (size_t)44 * 1024 * 1024);  // 44-50
    short* wqt_lo = (short*)(ws + (size_t)50 * 1024 * 1024);  // 50-56
    short* xhi    = (short*)(ws + (size_t)56 * 1024 * 1024);  // 56-64
    short* xlo    = (short*)(ws + (size_t)64 * 1024 * 1024);  // 64-72
    short* ctxhi  = (short*)(ws + (size_t)44 * 1024 * 1024);  // 44-52 (overlays dead wqt_hi)
    short* ctxlo  = (short*)(ws + (size_t)52 * 1024 * 1024);  // 52-60 (overlays dead wqt_lo/xhi)

    hipLaunchKernelGGL(split_x, dim3(32, 32), dim3(256), 0, stream, x, xhi, xlo);
    hipLaunchKernelGGL(prep_kernel, dim3(N3 / 64, 16), dim3(256), 0, stream,
                       Wq, Al, Bl, wqt_hi, wqt_lo, N3, 1);
    hipLaunchKernelGGL(prep_kernel, dim3(DD / 64, 16), dim3(256), 0, stream,
                       Wp, (const float*)nullptr, (const float*)nullptr,
                       wpt_hi, wpt_lo, DD, 0);
    hipLaunchKernelGGL(gemm3, dim3(N3 / 128, MR / 128), dim3(256), 0, stream,
                       xhi, xlo, wqt_hi, wqt_lo, bq,
                       qf, khi, klo, vt, (float*)nullptr, N3, 0);
    hipLaunchKernelGGL(attn_mfma, dim3(SS / 128, HH, BB), dim3(256), 0, stream,
                       qf, khi, klo, vt, ctxhi, ctxlo);
    hipLaunchKernelGGL(gemm3, dim3(DD / 128, MR / 128), dim3(256), 0, stream,
                       ctxhi, ctxlo, wpt_hi, wpt_lo, bp,
                       (float*)nullptr, (short*)nullptr, (short*)nullptr,
                       (short*)nullptr, (float*)d_out, DD, 1);
}

// Round 5
// 300.405 us; speedup vs baseline: 1.5739x; 1.0650x over previous
//
#include <hip/hip_runtime.h>
#include <hip/hip_bf16.h>

// B=2, S=2048, D=1024, H=16, HD=64, RANK=8, ALPHA=8. ALL I/O FP32.
// R17 = R16 with the short4 typedef renamed s16x4 (HIP header collision);
// otherwise identical. attn softmax/LDS restructured vs R15:
//  - swapped QK^T (mfma(K,Q)): lane owns one q-row, 16 keys in regs ->
//    softmax reduce = in-lane tree + 2 shfl_xor (was 32 shfl chains)
//  - K/V LDS key-slot XOR-swizzle (slot = idx ^ octet), baked into the
//    gemm3 epilogue global layout (gl_lds = identity copy) -> fragment
//    ds_read_b128 8-way bank conflict -> 2-way (free)
//  - Pt written as s16x4 (ds_write_b64 x4, was 16 scalar b16)
//  - s_setprio(1) around MFMA clusters
// ws (72 MB): qf 0-16 | khi 16-24 | klo 24-32 | vt 32-40 |
//             wpt hi 40-42 lo 42-44 | wqt hi 44-50 lo 50-56 |
//             xhi 56-64 xlo 64-72 | ctxhi 44-52 ctxlo 52-60 (overlay dead).

#define BB    2
#define SS    2048
#define DD    1024
#define HH    16
#define HDIM  64
#define N3    3072
#define MR    4096

typedef short short8 __attribute__((ext_vector_type(8)));
typedef short s16x4 __attribute__((ext_vector_type(4)));
typedef float f32x4 __attribute__((ext_vector_type(4)));

#define MFMA16(a, b, c) __builtin_amdgcn_mfma_f32_16x16x32_bf16((a), (b), (c), 0, 0, 0)

__device__ __forceinline__ float b2f(short s) {
    union { unsigned int u; float f; } c;
    c.u = ((unsigned int)(unsigned short)s) << 16;
    return c.f;
}
__device__ __forceinline__ short f2b(float f) {
    union { __hip_bfloat16 h; short s; } c;
    c.h = __float2bfloat16(f);
    return c.s;
}
struct HiLo { short hi, lo; };
__device__ __forceinline__ HiLo split2(float v) {
    HiLo r;
    r.hi = f2b(v);
    r.lo = f2b(v - b2f(r.hi));   // exact residual; next 8 mantissa bits
    return r;
}

__device__ __forceinline__ void gl_lds16(const void* g, void* l) {
    __builtin_amdgcn_global_load_lds(
        (const __attribute__((address_space(1))) void*)g,
        (__attribute__((address_space(3))) void*)l, 16, 0, 0);
}

// Tile-major offset for bf16 operand matrices consumed by gemm3:
// X[m][k] lives at ((m>>7)*32 + (k>>5))*4096 + ((k>>3)&3)*1024 + (m&127)*8 + (k&7)

// ---------------------------------------------------------------- split_x
// x fp32 [4096][1024] -> xhi/xlo bf16 tile-major. One block per (kchunk,panel).
__global__ __launch_bounds__(256) void split_x(const float* __restrict__ X,
                                               short* __restrict__ Xhi,
                                               short* __restrict__ Xlo) {
    int kc = blockIdx.x, p = blockIdx.y;
    int tid = threadIdx.x;
    int row = tid >> 1, half = tid & 1;
    const float* src = &X[((size_t)p * 128 + row) * 1024 + kc * 32 + half * 16];
    f32x4 v[4];
#pragma unroll
    for (int u = 0; u < 4; u++) v[u] = *(const f32x4*)(src + u * 4);
    size_t base = ((size_t)p * 32 + kc) * 4096 + (size_t)(half * 2) * 1024 + row * 8;
#pragma unroll
    for (int u = 0; u < 2; u++) {
        short8 h8, l8;
#pragma unroll
        for (int j = 0; j < 8; j++) {
            HiLo hl = split2(v[u * 2 + (j >> 2)][j & 3]);
            h8[j] = hl.hi; l8[j] = hl.lo;
        }
        *(short8*)&Xhi[base + u * 1024] = h8;
        *(short8*)&Xlo[base + u * 1024] = l8;
    }
}

// ---------------------------------------------------------------- prep
// Whi/Wlo = bf16split( W[k][n] + lora*8*sum_r A[k][r]*B[r][n] ), tile-major out.
__global__ __launch_bounds__(256) void prep_kernel(
    const float* __restrict__ W, const float* __restrict__ Al,
    const float* __restrict__ Bl, short* __restrict__ Whi,
    short* __restrict__ Wlo, int N, int lora)
{
    __shared__ float sw[64][68];
    __shared__ float sa[64][8];
    __shared__ float sb[8][64];
    int tid = threadIdx.x;
    int n0 = blockIdx.x * 64, k0 = blockIdx.y * 64;
#pragma unroll
    for (int p = 0; p < 4; p++) {
        int idx = p * 256 + tid;
        int kr = idx >> 4, ch = idx & 15;
        *(f32x4*)&sw[kr][ch * 4] = *(const f32x4*)&W[(size_t)(k0 + kr) * N + n0 + ch * 4];
    }
    if (lora) {
        if (tid < 64) {
#pragma unroll
            for (int r = 0; r < 8; r++) sa[tid][r] = Al[(k0 + tid) * 8 + r];
        } else if (tid < 128) {
            int c = tid - 64;
#pragma unroll
            for (int r = 0; r < 8; r++) sb[r][c] = Bl[(size_t)r * N + n0 + c];
        }
    }
    __syncthreads();
#pragma unroll
    for (int p = 0; p < 2; p++) {
        int idx = p * 256 + tid;
        int nr = idx >> 3, ch = idx & 7;
        short8 h8, l8;
#pragma unroll
        for (int j = 0; j < 8; j++) {
            int k = ch * 8 + j;
            float v = sw[k][nr];
            if (lora) {
                float a2 = 0.f;
#pragma unroll
                for (int r = 0; r < 8; r++) a2 += sa[k][r] * sb[r][nr];
                v += 8.0f * a2;
            }
            HiLo hl = split2(v);
            h8[j] = hl.hi;
            l8[j] = hl.lo;
        }
        int n = n0 + nr;
        int kchunk = (k0 >> 5) + (ch >> 2);
        size_t off = ((size_t)(n >> 7) * 32 + kchunk) * 4096 +
                     (size_t)(ch & 3) * 1024 + (n & 127) * 8;
        *(short8*)&Whi[off] = h8;
        *(short8*)&Wlo[off] = l8;
    }
}

// ---------------------------------------------------------------- gemm3
// C[m][n] = sum_k (Ahi+Alo)[m][k]*(Bhi+Blo)[n][k] (3-term hi/lo) + bias[n].
// mode 0 (QKV): n<1024 -> qf = v*0.125 (fp32); 1024..2047 -> khi/klo bf16
// split in attn-LDS layout (key-slot XOR-swizzled); >=2048 -> vt bf16 in
// attn-LDS layout (hd-slot XOR-swizzled). mode 1 (proj): outf32 row-major.
__global__ __launch_bounds__(256) void gemm3(
    const short* __restrict__ Ahi, const short* __restrict__ Alo,
    const short* __restrict__ Bhi, const short* __restrict__ Blo,
    const float* __restrict__ bias,
    float* __restrict__ qf, short* __restrict__ khi, short* __restrict__ klo,
    short* __restrict__ vt, float* __restrict__ outf32, int N, int mode)
{
    __shared__ short lds[4][4][128][8];   // arr(Ah,Al,Bh,Bl) x [q4][row][j]
    int tid = threadIdx.x;
    int wav = tid >> 6, lane = tid & 63;
    int l15 = lane & 15, q4 = lane >> 4;
    int wm = wav & 1, wn = wav >> 1;
    int n0 = blockIdx.x * 128, m0 = blockIdx.y * 128;

    const short* ga_h = Ahi + ((size_t)blockIdx.y * 32) * 4096 + tid * 8;
    const short* ga_l = Alo + ((size_t)blockIdx.y * 32) * 4096 + tid * 8;
    const short* gb_h = Bhi + ((size_t)blockIdx.x * 32) * 4096 + tid * 8;
    const short* gb_l = Blo + ((size_t)blockIdx.x * 32) * 4096 + tid * 8;
    short* l0 = &lds[0][0][0][0] + tid * 8;

    f32x4 acc[4][4] = {};

    for (int kc = 0; kc < 32; ++kc) {
        __syncthreads();               // previous iteration's frag reads done
        int koff = kc * 4096;
        gl_lds16(ga_h + koff,        l0);
        gl_lds16(ga_h + koff + 2048, l0 + 2048);
        gl_lds16(ga_l + koff,        l0 + 4096);
        gl_lds16(ga_l + koff + 2048, l0 + 6144);
        gl_lds16(gb_h + koff,        l0 + 8192);
        gl_lds16(gb_h + koff + 2048, l0 + 10240);
        gl_lds16(gb_l + koff,        l0 + 12288);
        gl_lds16(gb_l + koff + 2048, l0 + 14336);
        __syncthreads();               // vmcnt(0) drain: LDS tile ready
        short8 ah[4], al_[4], bh[4], bl[4];
#pragma unroll
        for (int i = 0; i < 4; i++) {
            ah[i]  = *(short8*)&lds[0][q4][wm * 64 + i * 16 + l15][0];
            al_[i] = *(short8*)&lds[1][q4][wm * 64 + i * 16 + l15][0];
            bh[i]  = *(short8*)&lds[2][q4][wn * 64 + i * 16 + l15][0];
            bl[i]  = *(short8*)&lds[3][q4][wn * 64 + i * 16 + l15][0];
        }
#pragma unroll
        for (int mi = 0; mi < 4; mi++)
#pragma unroll
            for (int ni = 0; ni < 4; ni++) {
                acc[mi][ni] = MFMA16(ah[mi], bh[ni], acc[mi][ni]);
                acc[mi][ni] = MFMA16(ah[mi], bl[ni], acc[mi][ni]);
                acc[mi][ni] = MFMA16(al_[mi], bh[ni], acc[mi][ni]);
            }
    }
#pragma unroll
    for (int ni = 0; ni < 4; ni++) {
        int n = n0 + wn * 64 + ni * 16 + l15;
        float bv = bias[n];
#pragma unroll
        for (int mi = 0; mi < 4; mi++) {
            int mbase = m0 + wm * 64 + mi * 16 + q4 * 4;
#pragma unroll
            for (int r = 0; r < 4; r++) {
                int m = mbase + r;
                float v = acc[mi][ni][r] + bv;
                if (mode != 0) {
                    outf32[(size_t)m * 1024 + n] = v;
                } else if (n0 < 1024) {
                    qf[(size_t)m * 1024 + n] = v * 0.125f;   // pow2: exact
                } else if (n0 < 2048) {
                    int kk = n - 1024, hh = kk >> 6, hd = kk & 63;
                    int bb_ = m >> 11, s = m & 2047;
                    int oct = hd >> 3;
                    size_t base = ((size_t)((bb_ << 4) + hh) * 32 + (s >> 6)) * 4096
                                  + (size_t)oct * 512 + ((s & 63) ^ oct) * 8 + (hd & 7);
                    HiLo hl = split2(v);
                    khi[base] = hl.hi;
                    klo[base] = hl.lo;
                } else {
                    int kk = n - 2048, hh = kk >> 6, hd = kk & 63;
                    int bb_ = m >> 11, s = m & 2047;
                    int oct = (s >> 3) & 7;
                    size_t base = ((size_t)((bb_ << 4) + hh) * 32 + (s >> 6)) * 4096
                                  + (size_t)oct * 512 + (hd ^ oct) * 8 + (s & 7);
                    vt[base] = f2b(v);
                }
            }
        }
    }
}

// ---------------------------------------------------------------- attn_mfma
// grid (S/128, H, B) = 512 blocks; block x processes q-tiles {31-x, x}.
// K/V staged via 6 linear global_load_lds_dwordx4 per chunk (dbuf, 1 barrier).
// Swapped QK^T (mfma(K,Q)): lane owns q-row l15, 16 keys in regs -> in-lane
// softmax + 2 shfl_xor. K/V LDS slots XOR-swizzled (written upstream).
__global__ __launch_bounds__(256) void attn_mfma(const float* __restrict__ qf,
                                                 const short* __restrict__ khi,
                                                 const short* __restrict__ klo,
                                                 const short* __restrict__ vtg,
                                                 short* __restrict__ ctxhi,
                                                 short* __restrict__ ctxlo) {
    __shared__ short KhL[2][4096];      // [buf][oct*512 + (key^oct)*8 + (hd&7)]
    __shared__ short KlL[2][4096];
    __shared__ short VtL[2][4096];      // [buf][oct*512 + (hd^oct)*8 + (key&7)]
    __shared__ short Pt[4][8][17][8];   // [wave][key-octet][qrow(+pad)][j]

    int h = blockIdx.y, b = blockIdx.z;
    int tid = threadIdx.x, wav = tid >> 6, lane = tid & 63;
    int l15 = lane & 15, q4 = lane >> 4;
    const float* bq = qf + (size_t)b * SS * 1024;
    size_t hb = (size_t)((b * 16 + h) * 32) * 4096;
    const short* gkh = khi + hb;
    const short* gkl = klo + hb;
    const short* gvt = vtg + hb;
    int t8 = tid * 8;

#define ISSUE(c, buf)                                                   \
    {                                                                   \
        size_t co_ = (size_t)(c) * 4096 + t8;                           \
        gl_lds16(gkh + co_,        &KhL[buf][t8]);                      \
        gl_lds16(gkh + co_ + 2048, &KhL[buf][t8 + 2048]);               \
        gl_lds16(gkl + co_,        &KlL[buf][t8]);                      \
        gl_lds16(gkl + co_ + 2048, &KlL[buf][t8 + 2048]);               \
        gl_lds16(gvt + co_,        &VtL[buf][t8]);                      \
        gl_lds16(gvt + co_ + 2048, &VtL[buf][t8 + 2048]);               \
    }

    for (int t = 0; t < 2; ++t) {
        int qt = t ? (int)blockIdx.x : 31 - (int)blockIdx.x;
        int qb = qt * 64;

        // Q fragments (values pre-scaled by 0.125 in gemm3 epilogue)
        size_t qoff = (size_t)(qb + wav * 16 + l15) * 1024 + h * 64;
        short8 q0h, q0l, q1h, q1l;
        {
            f32x4 a0 = *(const f32x4*)&bq[qoff + q4 * 8];
            f32x4 a1 = *(const f32x4*)&bq[qoff + q4 * 8 + 4];
            f32x4 c0 = *(const f32x4*)&bq[qoff + 32 + q4 * 8];
            f32x4 c1 = *(const f32x4*)&bq[qoff + 32 + q4 * 8 + 4];
#pragma unroll
            for (int j = 0; j < 4; j++) {
                HiLo u = split2(a0[j]); q0h[j] = u.hi; q0l[j] = u.lo;
                HiLo v = split2(a1[j]); q0h[4 + j] = v.hi; q0l[4 + j] = v.lo;
                HiLo w = split2(c0[j]); q1h[j] = w.hi; q1l[j] = w.lo;
                HiLo z = split2(c1[j]); q1h[4 + j] = z.hi; q1l[4 + j] = z.lo;
            }
        }

        f32x4 o[4] = {};
        float msc = -1e30f;    // running max for q-row l15 (per lane)
        float lsc = 0.f;       // running sum for q-row l15
        int nch = qt + 1;

        ISSUE(0, 0);
        __syncthreads();    // implicit vmcnt(0): chunk 0 staged

        for (int c = 0; c < nch; ++c) {
            int cur = c & 1;
            int k0 = c * 64;

            if (c + 1 < nch) ISSUE(c + 1, cur ^ 1);

            // ---- scores^T via mfma(K, Q): row = key (q4*4+r), col = qrow (l15)
            f32x4 s[4];
            __builtin_amdgcn_s_setprio(1);
#pragma unroll
            for (int g = 0; g < 4; g++) {
                int ko  = q4 * 512 + ((g * 16 + l15) ^ q4) * 8;
                int ko2 = (4 + q4) * 512 + ((g * 16 + l15) ^ (4 + q4)) * 8;
                short8 k0h_ = *(short8*)&KhL[cur][ko];
                short8 k0l_ = *(short8*)&KlL[cur][ko];
                short8 k1h_ = *(short8*)&KhL[cur][ko2];
                short8 k1l_ = *(short8*)&KlL[cur][ko2];
                f32x4 acc = {};
                acc = MFMA16(k0h_, q0h, acc);
                acc = MFMA16(k0l_, q0h, acc);
                acc = MFMA16(k0h_, q0l, acc);
                acc = MFMA16(k1h_, q1h, acc);
                acc = MFMA16(k1l_, q1h, acc);
                acc = MFMA16(k1h_, q1l, acc);
                s[g] = acc;
            }
            __builtin_amdgcn_s_setprio(0);

            // ---- online softmax: lane owns q-row l15; keys g*16+q4*4+r in regs
            if (c == qt) {            // diagonal chunk: causal mask
                int q = qb + wav * 16 + l15;
#pragma unroll
                for (int g = 0; g < 4; g++)
#pragma unroll
                    for (int r = 0; r < 4; r++)
                        if (k0 + g * 16 + q4 * 4 + r > q) s[g][r] = -1e30f;
            }
            f32x4 mx4 = s[0];
#pragma unroll
            for (int g = 1; g < 4; g++) {
                mx4[0] = fmaxf(mx4[0], s[g][0]); mx4[1] = fmaxf(mx4[1], s[g][1]);
                mx4[2] = fmaxf(mx4[2], s[g][2]); mx4[3] = fmaxf(mx4[3], s[g][3]);
            }
            float mx = fmaxf(fmaxf(mx4[0], mx4[1]), fmaxf(mx4[2], mx4[3]));
            mx = fmaxf(mx, __shfl_xor(mx, 16, 64));
            mx = fmaxf(mx, __shfl_xor(mx, 32, 64));
            float mn = fmaxf(msc, mx);
            f32x4 ps = {};
#pragma unroll
            for (int g = 0; g < 4; g++) {
                s16x4 pb;
#pragma unroll
                for (int r = 0; r < 4; r++) {
                    float p = __expf(s[g][r] - mn);
                    ps[r] += p;
                    pb[r] = f2b(p);
                }
                *(s16x4*)&Pt[wav][g * 2 + (q4 >> 1)][l15][(q4 & 1) * 4] = pb;
            }
            float sm = (ps[0] + ps[1]) + (ps[2] + ps[3]);
            sm += __shfl_xor(sm, 16, 64);
            sm += __shfl_xor(sm, 32, 64);
            float alpha_s = __expf(msc - mn);
            msc = mn;
            lsc = lsc * alpha_s + sm;
            float al0 = __shfl(alpha_s, q4 * 4 + 0, 64);
            float al1 = __shfl(alpha_s, q4 * 4 + 1, 64);
            float al2 = __shfl(alpha_s, q4 * 4 + 2, 64);
            float al3 = __shfl(alpha_s, q4 * 4 + 3, 64);

            // ---- PV: A = P (keys 0..31 / 32..63), B = V^T (swizzled slots)
            short8 pf0 = *(short8*)&Pt[wav][q4][l15][0];
            short8 pf1 = *(short8*)&Pt[wav][4 + q4][l15][0];
            __builtin_amdgcn_s_setprio(1);
#pragma unroll
            for (int gg = 0; gg < 4; gg++) {
                int vo  = q4 * 512 + ((gg * 16 + l15) ^ q4) * 8;
                int vo2 = (4 + q4) * 512 + ((gg * 16 + l15) ^ (4 + q4)) * 8;
                short8 vf0 = *(short8*)&VtL[cur][vo];
                short8 vf1 = *(short8*)&VtL[cur][vo2];
                f32x4 tt = o[gg];
                tt[0] *= al0; tt[1] *= al1; tt[2] *= al2; tt[3] *= al3;
                tt = MFMA16(pf0, vf0, tt);
                tt = MFMA16(pf1, vf1, tt);
                o[gg] = tt;
            }
            __builtin_amdgcn_s_setprio(0);

            __syncthreads();   // drains next-chunk gl_lds; orders buffer reuse
        }

        float ls0 = __shfl(lsc, q4 * 4 + 0, 64);
        float ls1 = __shfl(lsc, q4 * 4 + 1, 64);
        float ls2 = __shfl(lsc, q4 * 4 + 2, 64);
        float ls3 = __shfl(lsc, q4 * 4 + 3, 64);
        float lsr[4] = {ls0, ls1, ls2, ls3};
#pragma unroll
        for (int gg = 0; gg < 4; gg++)
#pragma unroll
            for (int r = 0; r < 4; r++) {
                int q = qb + wav * 16 + q4 * 4 + r;
                int mrow = b * SS + q;
                int k = h * 64 + gg * 16 + l15;
                HiLo hl = split2(o[gg][r] / lsr[r]);
                size_t off = ((size_t)(mrow >> 7) * 32 + (k >> 5)) * 4096 +
                             (size_t)((k >> 3) & 3) * 1024 + (mrow & 127) * 8 + (k & 7);
                ctxhi[off] = hl.hi;
                ctxlo[off] = hl.lo;
            }
    }
#undef ISSUE
}

extern "C" void kernel_launch(void* const* d_in, const int* in_sizes, int n_in,
                              void* d_out, int out_size, void* d_ws, size_t ws_size,
                              hipStream_t stream) {
    const float* x  = (const float*)d_in[0];
    const float* Wq = (const float*)d_in[1];
    const float* bq = (const float*)d_in[2];
    const float* Al = (const float*)d_in[3];
    const float* Bl = (const float*)d_in[4];
    const float* Wp = (const float*)d_in[5];
    const float* bp = (const float*)d_in[6];

    char* ws = (char*)d_ws;
    float* qf     = (float*)(ws);                             // 0-16 MB
    short* khi    = (short*)(ws + (size_t)16 * 1024 * 1024);  // 16-24
    short* klo    = (short*)(ws + (size_t)24 * 1024 * 1024);  // 24-32
    short* vt     = (short*)(ws + (size_t)32 * 1024 * 1024);  // 32-40
    short* wpt_hi = (short*)(ws + (size_t)40 * 1024 * 1024);  // 40-42
    short* wpt_lo = (short*)(ws + (size_t)42 * 1024 * 1024);  // 42-44
    short* wqt_hi = (short*)(ws + (size_t)44 * 1024 * 1024);  // 44-50
    short* wqt_lo = (short*)(ws + (size_t)50 * 1024 * 1024);  // 50-56
    short* xhi    = (short*)(ws + (size_t)56 * 1024 * 1024);  // 56-64
    short* xlo    = (short*)(ws + (size_t)64 * 1024 * 1024);  // 64-72
    short* ctxhi  = (short*)(ws + (size_t)44 * 1024 * 1024);  // 44-52 (overlays dead wqt_hi)
    short* ctxlo  = (short*)(ws + (size_t)52 * 1024 * 1024);  // 52-60 (overlays dead wqt_lo/xhi)

    hipLaunchKernelGGL(split_x, dim3(32, 32), dim3(256), 0, stream, x, xhi, xlo);
    hipLaunchKernelGGL(prep_kernel, dim3(N3 / 64, 16), dim3(256), 0, stream,
                       Wq, Al, Bl, wqt_hi, wqt_lo, N3, 1);
    hipLaunchKernelGGL(prep_kernel, dim3(DD / 64, 16), dim3(256), 0, stream,
                       Wp, (const float*)nullptr, (const float*)nullptr,
                       wpt_hi, wpt_lo, DD, 0);
    hipLaunchKernelGGL(gemm3, dim3(N3 / 128, MR / 128), dim3(256), 0, stream,
                       xhi, xlo, wqt_hi, wqt_lo, bq,
                       qf, khi, klo, vt, (float*)nullptr, N3, 0);
    hipLaunchKernelGGL(attn_mfma, dim3(SS / 128, HH, BB), dim3(256), 0, stream,
                       qf, khi, klo, vt, ctxhi, ctxlo);
    hipLaunchKernelGGL(gemm3, dim3(DD / 128, MR / 128), dim3(256), 0, stream,
                       ctxhi, ctxlo, wpt_hi, wpt_lo, bp,
                       (float*)nullptr, (short*)nullptr, (short*)nullptr,
                       (short*)nullptr, (float*)d_out, DD, 1);
}

// Round 6
// 278.996 us; speedup vs baseline: 1.6947x; 1.0767x over previous
//
#include <hip/hip_runtime.h>
#include <hip/hip_bf16.h>

// B=2, S=2048, D=1024, H=16, HD=64, RANK=8, ALPHA=8. ALL I/O FP32.
// R18 = R17 with gemm3's K-loop double-buffered (attn-R13 pattern):
//  - LDS tile 32KB -> 2x32KB dbuf; STAGE(k+1) issued at TOP of iteration k
//    (8 gl_lds16 travel during ~1000cy of ds_read+MFMA), ONE barrier/K-step
//    (was: issue->barrier-drain->compute = full L2 latency exposed/K-step)
//  - everything else byte-identical to R17 (attn swapped-QK^T + XOR-swizzle,
//    pre-split operands, tile-major gl_lds staging)
// ws (72 MB): qf 0-16 | khi 16-24 | klo 24-32 | vt 32-40 |
//             wpt hi 40-42 lo 42-44 | wqt hi 44-50 lo 50-56 |
//             xhi 56-64 xlo 64-72 | ctxhi 44-52 ctxlo 52-60 (overlay dead).

#define BB    2
#define SS    2048
#define DD    1024
#define HH    16
#define HDIM  64
#define N3    3072
#define MR    4096

typedef short short8 __attribute__((ext_vector_type(8)));
typedef short s16x4 __attribute__((ext_vector_type(4)));
typedef float f32x4 __attribute__((ext_vector_type(4)));

#define MFMA16(a, b, c) __builtin_amdgcn_mfma_f32_16x16x32_bf16((a), (b), (c), 0, 0, 0)

__device__ __forceinline__ float b2f(short s) {
    union { unsigned int u; float f; } c;
    c.u = ((unsigned int)(unsigned short)s) << 16;
    return c.f;
}
__device__ __forceinline__ short f2b(float f) {
    union { __hip_bfloat16 h; short s; } c;
    c.h = __float2bfloat16(f);
    return c.s;
}
struct HiLo { short hi, lo; };
__device__ __forceinline__ HiLo split2(float v) {
    HiLo r;
    r.hi = f2b(v);
    r.lo = f2b(v - b2f(r.hi));   // exact residual; next 8 mantissa bits
    return r;
}

__device__ __forceinline__ void gl_lds16(const void* g, void* l) {
    __builtin_amdgcn_global_load_lds(
        (const __attribute__((address_space(1))) void*)g,
        (__attribute__((address_space(3))) void*)l, 16, 0, 0);
}

// Tile-major offset for bf16 operand matrices consumed by gemm3:
// X[m][k] lives at ((m>>7)*32 + (k>>5))*4096 + ((k>>3)&3)*1024 + (m&127)*8 + (k&7)

// ---------------------------------------------------------------- split_x
// x fp32 [4096][1024] -> xhi/xlo bf16 tile-major. One block per (kchunk,panel).
__global__ __launch_bounds__(256) void split_x(const float* __restrict__ X,
                                               short* __restrict__ Xhi,
                                               short* __restrict__ Xlo) {
    int kc = blockIdx.x, p = blockIdx.y;
    int tid = threadIdx.x;
    int row = tid >> 1, half = tid & 1;
    const float* src = &X[((size_t)p * 128 + row) * 1024 + kc * 32 + half * 16];
    f32x4 v[4];
#pragma unroll
    for (int u = 0; u < 4; u++) v[u] = *(const f32x4*)(src + u * 4);
    size_t base = ((size_t)p * 32 + kc) * 4096 + (size_t)(half * 2) * 1024 + row * 8;
#pragma unroll
    for (int u = 0; u < 2; u++) {
        short8 h8, l8;
#pragma unroll
        for (int j = 0; j < 8; j++) {
            HiLo hl = split2(v[u * 2 + (j >> 2)][j & 3]);
            h8[j] = hl.hi; l8[j] = hl.lo;
        }
        *(short8*)&Xhi[base + u * 1024] = h8;
        *(short8*)&Xlo[base + u * 1024] = l8;
    }
}

// ---------------------------------------------------------------- prep
// Whi/Wlo = bf16split( W[k][n] + lora*8*sum_r A[k][r]*B[r][n] ), tile-major out.
__global__ __launch_bounds__(256) void prep_kernel(
    const float* __restrict__ W, const float* __restrict__ Al,
    const float* __restrict__ Bl, short* __restrict__ Whi,
    short* __restrict__ Wlo, int N, int lora)
{
    __shared__ float sw[64][68];
    __shared__ float sa[64][8];
    __shared__ float sb[8][64];
    int tid = threadIdx.x;
    int n0 = blockIdx.x * 64, k0 = blockIdx.y * 64;
#pragma unroll
    for (int p = 0; p < 4; p++) {
        int idx = p * 256 + tid;
        int kr = idx >> 4, ch = idx & 15;
        *(f32x4*)&sw[kr][ch * 4] = *(const f32x4*)&W[(size_t)(k0 + kr) * N + n0 + ch * 4];
    }
    if (lora) {
        if (tid < 64) {
#pragma unroll
            for (int r = 0; r < 8; r++) sa[tid][r] = Al[(k0 + tid) * 8 + r];
        } else if (tid < 128) {
            int c = tid - 64;
#pragma unroll
            for (int r = 0; r < 8; r++) sb[r][c] = Bl[(size_t)r * N + n0 + c];
        }
    }
    __syncthreads();
#pragma unroll
    for (int p = 0; p < 2; p++) {
        int idx = p * 256 + tid;
        int nr = idx >> 3, ch = idx & 7;
        short8 h8, l8;
#pragma unroll
        for (int j = 0; j < 8; j++) {
            int k = ch * 8 + j;
            float v = sw[k][nr];
            if (lora) {
                float a2 = 0.f;
#pragma unroll
                for (int r = 0; r < 8; r++) a2 += sa[k][r] * sb[r][nr];
                v += 8.0f * a2;
            }
            HiLo hl = split2(v);
            h8[j] = hl.hi;
            l8[j] = hl.lo;
        }
        int n = n0 + nr;
        int kchunk = (k0 >> 5) + (ch >> 2);
        size_t off = ((size_t)(n >> 7) * 32 + kchunk) * 4096 +
                     (size_t)(ch & 3) * 1024 + (n & 127) * 8;
        *(short8*)&Whi[off] = h8;
        *(short8*)&Wlo[off] = l8;
    }
}

// ---------------------------------------------------------------- gemm3
// C[m][n] = sum_k (Ahi+Alo)[m][k]*(Bhi+Blo)[n][k] (3-term hi/lo) + bias[n].
// Double-buffered LDS; K-step t+1's 8 gl_lds16 issued before t's compute;
// one barrier per K-step. mode 0 (QKV): n<1024 -> qf = v*0.125 (fp32);
// 1024..2047 -> khi/klo bf16 split, attn-LDS layout (key-slot XOR-swizzled);
// >=2048 -> vt bf16, attn-LDS layout (hd-slot XOR-swizzled).
// mode 1 (proj): outf32 row-major.
__global__ __launch_bounds__(256) void gemm3(
    const short* __restrict__ Ahi, const short* __restrict__ Alo,
    const short* __restrict__ Bhi, const short* __restrict__ Blo,
    const float* __restrict__ bias,
    float* __restrict__ qf, short* __restrict__ khi, short* __restrict__ klo,
    short* __restrict__ vt, float* __restrict__ outf32, int N, int mode)
{
    __shared__ short lds[2][4][4][128][8];  // [dbuf][mat(Ah,Al,Bh,Bl)][q4][row][j]
    int tid = threadIdx.x;
    int wav = tid >> 6, lane = tid & 63;
    int l15 = lane & 15, q4 = lane >> 4;
    int wm = wav & 1, wn = wav >> 1;
    int n0 = blockIdx.x * 128, m0 = blockIdx.y * 128;

    const short* ga_h = Ahi + ((size_t)blockIdx.y * 32) * 4096 + tid * 8;
    const short* ga_l = Alo + ((size_t)blockIdx.y * 32) * 4096 + tid * 8;
    const short* gb_h = Bhi + ((size_t)blockIdx.x * 32) * 4096 + tid * 8;
    const short* gb_l = Blo + ((size_t)blockIdx.x * 32) * 4096 + tid * 8;
    short* l0 = &lds[0][0][0][0][0] + tid * 8;

    f32x4 acc[4][4] = {};

#define STAGE(kc_, buf_)                                         \
    {                                                            \
        int koff_ = (kc_) * 4096;                                \
        short* lb_ = l0 + (buf_) * 16384;                        \
        gl_lds16(ga_h + koff_,        lb_);                      \
        gl_lds16(ga_h + koff_ + 2048, lb_ + 2048);               \
        gl_lds16(ga_l + koff_,        lb_ + 4096);               \
        gl_lds16(ga_l + koff_ + 2048, lb_ + 6144);               \
        gl_lds16(gb_h + koff_,        lb_ + 8192);               \
        gl_lds16(gb_h + koff_ + 2048, lb_ + 10240);              \
        gl_lds16(gb_l + koff_,        lb_ + 12288);              \
        gl_lds16(gb_l + koff_ + 2048, lb_ + 14336);              \
    }

    STAGE(0, 0);
    __syncthreads();               // implicit vmcnt(0): K-step 0 staged

    for (int kc = 0; kc < 32; ++kc) {
        int cur = kc & 1;
        if (kc + 1 < 32) STAGE(kc + 1, cur ^ 1);   // travels under compute
        short8 ah[4], al_[4], bh[4], bl[4];
#pragma unroll
        for (int i = 0; i < 4; i++) {
            ah[i]  = *(short8*)&lds[cur][0][q4][wm * 64 + i * 16 + l15][0];
            al_[i] = *(short8*)&lds[cur][1][q4][wm * 64 + i * 16 + l15][0];
            bh[i]  = *(short8*)&lds[cur][2][q4][wn * 64 + i * 16 + l15][0];
            bl[i]  = *(short8*)&lds[cur][3][q4][wn * 64 + i * 16 + l15][0];
        }
#pragma unroll
        for (int mi = 0; mi < 4; mi++)
#pragma unroll
            for (int ni = 0; ni < 4; ni++) {
                acc[mi][ni] = MFMA16(ah[mi], bh[ni], acc[mi][ni]);
                acc[mi][ni] = MFMA16(ah[mi], bl[ni], acc[mi][ni]);
                acc[mi][ni] = MFMA16(al_[mi], bh[ni], acc[mi][ni]);
            }
        __syncthreads();           // drains K+1 loads (issued pre-compute) +
                                   // all waves done reading lds[cur]
    }
#undef STAGE
#pragma unroll
    for (int ni = 0; ni < 4; ni++) {
        int n = n0 + wn * 64 + ni * 16 + l15;
        float bv = bias[n];
#pragma unroll
        for (int mi = 0; mi < 4; mi++) {
            int mbase = m0 + wm * 64 + mi * 16 + q4 * 4;
#pragma unroll
            for (int r = 0; r < 4; r++) {
                int m = mbase + r;
                float v = acc[mi][ni][r] + bv;
                if (mode != 0) {
                    outf32[(size_t)m * 1024 + n] = v;
                } else if (n0 < 1024) {
                    qf[(size_t)m * 1024 + n] = v * 0.125f;   // pow2: exact
                } else if (n0 < 2048) {
                    int kk = n - 1024, hh = kk >> 6, hd = kk & 63;
                    int bb_ = m >> 11, s = m & 2047;
                    int oct = hd >> 3;
                    size_t base = ((size_t)((bb_ << 4) + hh) * 32 + (s >> 6)) * 4096
                                  + (size_t)oct * 512 + ((s & 63) ^ oct) * 8 + (hd & 7);
                    HiLo hl = split2(v);
                    khi[base] = hl.hi;
                    klo[base] = hl.lo;
                } else {
                    int kk = n - 2048, hh = kk >> 6, hd = kk & 63;
                    int bb_ = m >> 11, s = m & 2047;
                    int oct = (s >> 3) & 7;
                    size_t base = ((size_t)((bb_ << 4) + hh) * 32 + (s >> 6)) * 4096
                                  + (size_t)oct * 512 + (hd ^ oct) * 8 + (s & 7);
                    vt[base] = f2b(v);
                }
            }
        }
    }
}

// ---------------------------------------------------------------- attn_mfma
// grid (S/128, H, B) = 512 blocks; block x processes q-tiles {31-x, x}.
// K/V staged via 6 linear global_load_lds_dwordx4 per chunk (dbuf, 1 barrier).
// Swapped QK^T (mfma(K,Q)): lane owns q-row l15, 16 keys in regs -> in-lane
// softmax + 2 shfl_xor. K/V LDS slots XOR-swizzled (written upstream).
__global__ __launch_bounds__(256) void attn_mfma(const float* __restrict__ qf,
                                                 const short* __restrict__ khi,
                                                 const short* __restrict__ klo,
                                                 const short* __restrict__ vtg,
                                                 short* __restrict__ ctxhi,
                                                 short* __restrict__ ctxlo) {
    __shared__ short KhL[2][4096];      // [buf][oct*512 + (key^oct)*8 + (hd&7)]
    __shared__ short KlL[2][4096];
    __shared__ short VtL[2][4096];      // [buf][oct*512 + (hd^oct)*8 + (key&7)]
    __shared__ short Pt[4][8][17][8];   // [wave][key-octet][qrow(+pad)][j]

    int h = blockIdx.y, b = blockIdx.z;
    int tid = threadIdx.x, wav = tid >> 6, lane = tid & 63;
    int l15 = lane & 15, q4 = lane >> 4;
    const float* bq = qf + (size_t)b * SS * 1024;
    size_t hb = (size_t)((b * 16 + h) * 32) * 4096;
    const short* gkh = khi + hb;
    const short* gkl = klo + hb;
    const short* gvt = vtg + hb;
    int t8 = tid * 8;

#define ISSUE(c, buf)                                                   \
    {                                                                   \
        size_t co_ = (size_t)(c) * 4096 + t8;                           \
        gl_lds16(gkh + co_,        &KhL[buf][t8]);                      \
        gl_lds16(gkh + co_ + 2048, &KhL[buf][t8 + 2048]);               \
        gl_lds16(gkl + co_,        &KlL[buf][t8]);                      \
        gl_lds16(gkl + co_ + 2048, &KlL[buf][t8 + 2048]);               \
        gl_lds16(gvt + co_,        &VtL[buf][t8]);                      \
        gl_lds16(gvt + co_ + 2048, &VtL[buf][t8 + 2048]);               \
    }

    for (int t = 0; t < 2; ++t) {
        int qt = t ? (int)blockIdx.x : 31 - (int)blockIdx.x;
        int qb = qt * 64;

        // Q fragments (values pre-scaled by 0.125 in gemm3 epilogue)
        size_t qoff = (size_t)(qb + wav * 16 + l15) * 1024 + h * 64;
        short8 q0h, q0l, q1h, q1l;
        {
            f32x4 a0 = *(const f32x4*)&bq[qoff + q4 * 8];
            f32x4 a1 = *(const f32x4*)&bq[qoff + q4 * 8 + 4];
            f32x4 c0 = *(const f32x4*)&bq[qoff + 32 + q4 * 8];
            f32x4 c1 = *(const f32x4*)&bq[qoff + 32 + q4 * 8 + 4];
#pragma unroll
            for (int j = 0; j < 4; j++) {
                HiLo u = split2(a0[j]); q0h[j] = u.hi; q0l[j] = u.lo;
                HiLo v = split2(a1[j]); q0h[4 + j] = v.hi; q0l[4 + j] = v.lo;
                HiLo w = split2(c0[j]); q1h[j] = w.hi; q1l[j] = w.lo;
                HiLo z = split2(c1[j]); q1h[4 + j] = z.hi; q1l[4 + j] = z.lo;
            }
        }

        f32x4 o[4] = {};
        float msc = -1e30f;    // running max for q-row l15 (per lane)
        float lsc = 0.f;       // running sum for q-row l15
        int nch = qt + 1;

        ISSUE(0, 0);
        __syncthreads();    // implicit vmcnt(0): chunk 0 staged

        for (int c = 0; c < nch; ++c) {
            int cur = c & 1;
            int k0 = c * 64;

            if (c + 1 < nch) ISSUE(c + 1, cur ^ 1);

            // ---- scores^T via mfma(K, Q): row = key (q4*4+r), col = qrow (l15)
            f32x4 s[4];
            __builtin_amdgcn_s_setprio(1);
#pragma unroll
            for (int g = 0; g < 4; g++) {
                int ko  = q4 * 512 + ((g * 16 + l15) ^ q4) * 8;
                int ko2 = (4 + q4) * 512 + ((g * 16 + l15) ^ (4 + q4)) * 8;
                short8 k0h_ = *(short8*)&KhL[cur][ko];
                short8 k0l_ = *(short8*)&KlL[cur][ko];
                short8 k1h_ = *(short8*)&KhL[cur][ko2];
                short8 k1l_ = *(short8*)&KlL[cur][ko2];
                f32x4 acc = {};
                acc = MFMA16(k0h_, q0h, acc);
                acc = MFMA16(k0l_, q0h, acc);
                acc = MFMA16(k0h_, q0l, acc);
                acc = MFMA16(k1h_, q1h, acc);
                acc = MFMA16(k1l_, q1h, acc);
                acc = MFMA16(k1h_, q1l, acc);
                s[g] = acc;
            }
            __builtin_amdgcn_s_setprio(0);

            // ---- online softmax: lane owns q-row l15; keys g*16+q4*4+r in regs
            if (c == qt) {            // diagonal chunk: causal mask
                int q = qb + wav * 16 + l15;
#pragma unroll
                for (int g = 0; g < 4; g++)
#pragma unroll
                    for (int r = 0; r < 4; r++)
                        if (k0 + g * 16 + q4 * 4 + r > q) s[g][r] = -1e30f;
            }
            f32x4 mx4 = s[0];
#pragma unroll
            for (int g = 1; g < 4; g++) {
                mx4[0] = fmaxf(mx4[0], s[g][0]); mx4[1] = fmaxf(mx4[1], s[g][1]);
                mx4[2] = fmaxf(mx4[2], s[g][2]); mx4[3] = fmaxf(mx4[3], s[g][3]);
            }
            float mx = fmaxf(fmaxf(mx4[0], mx4[1]), fmaxf(mx4[2], mx4[3]));
            mx = fmaxf(mx, __shfl_xor(mx, 16, 64));
            mx = fmaxf(mx, __shfl_xor(mx, 32, 64));
            float mn = fmaxf(msc, mx);
            f32x4 ps = {};
#pragma unroll
            for (int g = 0; g < 4; g++) {
                s16x4 pb;
#pragma unroll
                for (int r = 0; r < 4; r++) {
                    float p = __expf(s[g][r] - mn);
                    ps[r] += p;
                    pb[r] = f2b(p);
                }
                *(s16x4*)&Pt[wav][g * 2 + (q4 >> 1)][l15][(q4 & 1) * 4] = pb;
            }
            float sm = (ps[0] + ps[1]) + (ps[2] + ps[3]);
            sm += __shfl_xor(sm, 16, 64);
            sm += __shfl_xor(sm, 32, 64);
            float alpha_s = __expf(msc - mn);
            msc = mn;
            lsc = lsc * alpha_s + sm;
            float al0 = __shfl(alpha_s, q4 * 4 + 0, 64);
            float al1 = __shfl(alpha_s, q4 * 4 + 1, 64);
            float al2 = __shfl(alpha_s, q4 * 4 + 2, 64);
            float al3 = __shfl(alpha_s, q4 * 4 + 3, 64);

            // ---- PV: A = P (keys 0..31 / 32..63), B = V^T (swizzled slots)
            short8 pf0 = *(short8*)&Pt[wav][q4][l15][0];
            short8 pf1 = *(short8*)&Pt[wav][4 + q4][l15][0];
            __builtin_amdgcn_s_setprio(1);
#pragma unroll
            for (int gg = 0; gg < 4; gg++) {
                int vo  = q4 * 512 + ((gg * 16 + l15) ^ q4) * 8;
                int vo2 = (4 + q4) * 512 + ((gg * 16 + l15) ^ (4 + q4)) * 8;
                short8 vf0 = *(short8*)&VtL[cur][vo];
                short8 vf1 = *(short8*)&VtL[cur][vo2];
                f32x4 tt = o[gg];
                tt[0] *= al0; tt[1] *= al1; tt[2] *= al2; tt[3] *= al3;
                tt = MFMA16(pf0, vf0, tt);
                tt = MFMA16(pf1, vf1, tt);
                o[gg] = tt;
            }
            __builtin_amdgcn_s_setprio(0);

            __syncthreads();   // drains next-chunk gl_lds; orders buffer reuse
        }

        float ls0 = __shfl(lsc, q4 * 4 + 0, 64);
        float ls1 = __shfl(lsc, q4 * 4 + 1, 64);
        float ls2 = __shfl(lsc, q4 * 4 + 2, 64);
        float ls3 = __shfl(lsc, q4 * 4 + 3, 64);
        float lsr[4] = {ls0, ls1, ls2, ls3};
#pragma unroll
        for (int gg = 0; gg < 4; gg++)
#pragma unroll
            for (int r = 0; r < 4; r++) {
                int q = qb + wav * 16 + q4 * 4 + r;
                int mrow = b * SS + q;
                int k = h * 64 + gg * 16 + l15;
                HiLo hl = split2(o[gg][r] / lsr[r]);
                size_t off = ((size_t)(mrow >> 7) * 32 + (k >> 5)) * 4096 +
                             (size_t)((k >> 3) & 3) * 1024 + (mrow & 127) * 8 + (k & 7);
                ctxhi[off] = hl.hi;
                ctxlo[off] = hl.lo;
            }
    }
#undef ISSUE
}

extern "C" void kernel_launch(void* const* d_in, const int* in_sizes, int n_in,
                              void* d_out, int out_size, void* d_ws, size_t ws_size,
                              hipStream_t stream) {
    const float* x  = (const float*)d_in[0];
    const float* Wq = (const float*)d_in[1];
    const float* bq = (const float*)d_in[2];
    const float* Al = (const float*)d_in[3];
    const float* Bl = (const float*)d_in[4];
    const float* Wp = (const float*)d_in[5];
    const float* bp = (const float*)d_in[6];

    char* ws = (char*)d_ws;
    float* qf     = (float*)(ws);                             // 0-16 MB
    short* khi    = (short*)(ws + (size_t)16 * 1024 * 1024);  // 16-24
    short* klo    = (short*)(ws + (size_t)24 * 1024 * 1024);  // 24-32
    short* vt     = (short*)(ws + (size_t)32 * 1024 * 1024);  // 32-40
    short* wpt_hi = (short*)(ws + (size_t)40 * 1024 * 1024);  // 40-42
    short* wpt_lo = (short*)(ws + (size_t)42 * 1024 * 1024);  // 42-44
    short* wqt_hi = (short*)(ws + (size_t)44 * 1024 * 1024);  // 44-50
    short* wqt_lo = (short*)(ws + (size_t)50 * 1024 * 1024);  // 50-56
    short* xhi    = (short*)(ws + (size_t)56 * 1024 * 1024);  // 56-64
    short* xlo    = (short*)(ws + (size_t)64 * 1024 * 1024);  // 64-72
    short* ctxhi  = (short*)(ws + (size_t)44 * 1024 * 1024);  // 44-52 (overlays dead wqt_hi)
    short* ctxlo  = (short*)(ws + (size_t)52 * 1024 * 1024);  // 52-60 (overlays dead wqt_lo/xhi)

    hipLaunchKernelGGL(split_x, dim3(32, 32), dim3(256), 0, stream, x, xhi, xlo);
    hipLaunchKernelGGL(prep_kernel, dim3(N3 / 64, 16), dim3(256), 0, stream,
                       Wq, Al, Bl, wqt_hi, wqt_lo, N3, 1);
    hipLaunchKernelGGL(prep_kernel, dim3(DD / 64, 16), dim3(256), 0, stream,
                       Wp, (const float*)nullptr, (const float*)nullptr,
                       wpt_hi, wpt_lo, DD, 0);
    hipLaunchKernelGGL(gemm3, dim3(N3 / 128, MR / 128), dim3(256), 0, stream,
                       xhi, xlo, wqt_hi, wqt_lo, bq,
                       qf, khi, klo, vt, (float*)nullptr, N3, 0);
    hipLaunchKernelGGL(attn_mfma, dim3(SS / 128, HH, BB), dim3(256), 0, stream,
                       qf, khi, klo, vt, ctxhi, ctxlo);
    hipLaunchKernelGGL(gemm3, dim3(DD / 128, MR / 128), dim3(256), 0, stream,
                       ctxhi, ctxlo, wpt_hi, wpt_lo, bp,
                       (float*)nullptr, (short*)nullptr, (short*)nullptr,
                       (short*)nullptr, (float*)d_out, DD, 1);
}